// Round 12
// baseline (114.035 us; speedup 1.0000x reference)
//
#include <hip/hip_runtime.h>
#include <hip/hip_bf16.h>

#define B_  2
#define T_  2048
#define D_  512
#define DM_ 64
#define H_  16
#define NQ_ (DM_*H_)   // 1024
#define NT_ (T_/64)    // 32 key tiles

typedef __bf16 bf16x8 __attribute__((ext_vector_type(8)));
typedef __bf16 bf16x4 __attribute__((ext_vector_type(4)));
typedef float  f32x4  __attribute__((ext_vector_type(4)));
typedef float  f32x16 __attribute__((ext_vector_type(16)));
typedef unsigned int u32;

static __device__ __forceinline__ __bf16 bfc(float x) { return (__bf16)x; }
static __device__ __forceinline__ unsigned short f2bf(float x) {
    __bf16 b = (__bf16)x;
    unsigned short u;
    __builtin_memcpy(&u, &b, 2);
    return u;
}
static __device__ __forceinline__ u32 pack2bf(float a, float b) {
    return (u32)f2bf(a) | ((u32)f2bf(b) << 16);
}

#if __has_builtin(__builtin_amdgcn_exp2f)
static __device__ __forceinline__ float EXP2(float x) { return __builtin_amdgcn_exp2f(x); }
#else
static __device__ __forceinline__ float EXP2(float x) {
    float r; asm("v_exp_f32 %0, %1\ns_nop 0" : "=v"(r) : "v"(x)); return r;
}
#endif

// async global->LDS, 16B per lane; dest = wave-uniform base + lane*16
#define GLOAD16(gp, lp) \
    __builtin_amdgcn_global_load_lds((const __attribute__((address_space(1))) u32*)(gp), \
                                     (__attribute__((address_space(3))) u32*)(lp), 16, 0, 0)

// ---------------------------------------------------------------------------
// fused prep: [0,1024) pad | [1024,2048) data cvt | [2048,3584) qkv wtrans |
// [3584,4096) wo wtrans
// ---------------------------------------------------------------------------
__global__ __launch_bounds__(256)
void prep_kernel(const float* __restrict__ mask, float* __restrict__ padb,
                 const float* __restrict__ data, unsigned short* __restrict__ dataB,
                 const float* __restrict__ wq, const float* __restrict__ wk,
                 const float* __restrict__ wv, unsigned short* __restrict__ btall,
                 const float* __restrict__ wo, unsigned short* __restrict__ wot)
{
    __shared__ float t[32][33];
    const int bid = blockIdx.x;
    const int tid = threadIdx.x;
    if (bid < 1024) {
        const int row  = bid * 4 + (tid >> 6);
        const int lane = tid & 63;
        const float* p = mask + (size_t)row * D_;
        float4 a = *(const float4*)&p[lane * 8];
        float4 b = *(const float4*)&p[lane * 8 + 4];
        float s = a.x + a.y + a.z + a.w + b.x + b.y + b.z + b.w;
#pragma unroll
        for (int off = 32; off; off >>= 1) s += __shfl_down(s, off);
        if (lane == 0) padb[row] = (s == 0.0f) ? -1e9f : 0.0f;
    } else if (bid < 2048) {
        int i = ((bid - 1024) * 256 + tid) * 8;
        float4 a = *(const float4*)&data[i];
        float4 b = *(const float4*)&data[i + 4];
        bf16x8 u = {bfc(a.x), bfc(a.y), bfc(a.z), bfc(a.w),
                    bfc(b.x), bfc(b.y), bfc(b.z), bfc(b.w)};
        *(bf16x8*)&dataB[i] = u;
    } else if (bid < 3584) {
        const int idx = bid - 2048;
        const int z = idx >> 9, rem = idx & 511;
        const int c0 = (rem & 31) * 32, r0 = (rem >> 5) * 32;   // C=1024, R=512
        const float* in = (z == 0) ? wq : (z == 1) ? wk : wv;
        unsigned short* out = btall + (size_t)z * NQ_ * D_;
        const int tx = tid & 31, ty = tid >> 5;
#pragma unroll
        for (int i = 0; i < 4; ++i)
            t[ty * 4 + i][tx] = in[(size_t)(r0 + ty * 4 + i) * NQ_ + c0 + tx];
        __syncthreads();
#pragma unroll
        for (int i = 0; i < 4; ++i)
            out[(size_t)(c0 + ty * 4 + i) * D_ + r0 + tx] = f2bf(t[tx][ty * 4 + i]);
    } else {
        const int idx = bid - 3584;
        const int c0 = (idx & 15) * 32, r0 = (idx >> 4) * 32;   // C=512, R=1024
        const int tx = tid & 31, ty = tid >> 5;
#pragma unroll
        for (int i = 0; i < 4; ++i)
            t[ty * 4 + i][tx] = wo[(size_t)(r0 + ty * 4 + i) * D_ + c0 + tx];
        __syncthreads();
#pragma unroll
        for (int i = 0; i < 4; ++i)
            wot[(size_t)(c0 + ty * 4 + i) * NQ_ + r0 + tx] = f2bf(t[tx][ty * 4 + i]);
    }
}

// ---------------------------------------------------------------------------
// fused QKV GEMM: A[4096,512] @ BtAll[3072,512]^T, gload_lds dbuf staging.
// seg 0 -> Qh head-major *alpha_q, 1 -> Kh head-major, 2 -> Vt transposed.
// ---------------------------------------------------------------------------
__global__ __launch_bounds__(256)
void mgemm_qkv_kernel(const unsigned short* __restrict__ A,
                      const unsigned short* __restrict__ BtAll,
                      const float* __restrict__ bq, const float* __restrict__ bk,
                      const float* __restrict__ bv,
                      unsigned short* __restrict__ Qh, unsigned short* __restrict__ Kh,
                      unsigned short* __restrict__ Vt, float alpha_q)
{
    const int K = D_;
    __shared__ __align__(16) unsigned short Al[2][128 * 64];
    __shared__ __align__(16) unsigned short Bl[2][128 * 64];

    const int tid = threadIdx.x;
    const int w  = tid >> 6, l = tid & 63;
    const int lo = l & 15,  g = l >> 4;
    const int wri = w >> 1, wci = w & 1;
    const int m0 = blockIdx.y * 128, n0 = blockIdx.x * 128;
    const int lrow = l >> 3;
    const int lslot = (l & 7) ^ lrow;     // pre-swizzled source slot

    f32x4 acc[4][4] = {};
    const int nk = K >> 6;   // 8

    // prologue: stage k-step 0 into buf0
#pragma unroll
    for (int p = 0; p < 4; ++p) {
        int br = w * 32 + p * 8;
        GLOAD16(A     + (size_t)(m0 + br + lrow) * K + lslot * 8, (char*)Al[0] + br * 128);
        GLOAD16(BtAll + (size_t)(n0 + br + lrow) * K + lslot * 8, (char*)Bl[0] + br * 128);
    }
    __syncthreads();

    for (int t = 0; t < nk; ++t) {
        const int cur = t & 1;
        if (t + 1 < nk) {
            const int k0 = (t + 1) << 6;
#pragma unroll
            for (int p = 0; p < 4; ++p) {
                int br = w * 32 + p * 8;
                GLOAD16(A     + (size_t)(m0 + br + lrow) * K + k0 + lslot * 8,
                        (char*)Al[cur ^ 1] + br * 128);
                GLOAD16(BtAll + (size_t)(n0 + br + lrow) * K + k0 + lslot * 8,
                        (char*)Bl[cur ^ 1] + br * 128);
            }
        }
#pragma unroll
        for (int kk = 0; kk < 2; ++kk) {
            bf16x8 af[4], bfr[4];
#pragma unroll
            for (int i = 0; i < 4; ++i) {
                int row = wri * 64 + i * 16 + lo;
                af[i] = *(const bf16x8*)&Al[cur][row * 64 + ((((kk << 2) + g) ^ (row & 7)) << 3)];
                int col = wci * 64 + i * 16 + lo;
                bfr[i] = *(const bf16x8*)&Bl[cur][col * 64 + ((((kk << 2) + g) ^ (col & 7)) << 3)];
            }
#pragma unroll
            for (int i = 0; i < 4; ++i)
#pragma unroll
                for (int j = 0; j < 4; ++j)
                    acc[i][j] = __builtin_amdgcn_mfma_f32_16x16x32_bf16(af[i], bfr[j], acc[i][j], 0, 0, 0);
        }
        __syncthreads();
    }

    const int seg = n0 >> 10;                  // 0:Q 1:K 2:V
    const int n0l = n0 & 1023;
    const float* bias = (seg == 0) ? bq : (seg == 1) ? bk : bv;
    const float alpha = (seg == 0) ? alpha_q : 1.0f;
    unsigned short* o16 = (seg == 0) ? Qh : (seg == 1) ? Kh : Vt;

    const int mb = m0 + wri * 64 + g * 4;
    float bb[4];
#pragma unroll
    for (int j = 0; j < 4; ++j) bb[j] = bias[n0l + wci * 64 + j * 16 + lo];
    const int head = lo;
    const int dmb  = (n0l >> 4) + wci * 4;
    if (seg < 2) {
#pragma unroll
        for (int i = 0; i < 4; ++i)
#pragma unroll
            for (int jj = 0; jj < 4; ++jj) {
                int m = mb + i * 16 + jj;
                int t = m & (T_ - 1), bidx = m >> 11;
                bf16x4 u = {bfc((acc[i][0][jj] + bb[0]) * alpha),
                            bfc((acc[i][1][jj] + bb[1]) * alpha),
                            bfc((acc[i][2][jj] + bb[2]) * alpha),
                            bfc((acc[i][3][jj] + bb[3]) * alpha)};
                *(bf16x4*)&o16[(((size_t)(bidx * H_ + head)) * T_ + t) * DM_ + dmb] = u;
            }
    } else {
#pragma unroll
        for (int i = 0; i < 4; ++i)
#pragma unroll
            for (int j = 0; j < 4; ++j) {
                int m = mb + i * 16;
                int t = m & (T_ - 1), bidx = m >> 11;
                bf16x4 u = {bfc(acc[i][j][0] + bb[j]), bfc(acc[i][j][1] + bb[j]),
                            bfc(acc[i][j][2] + bb[j]), bfc(acc[i][j][3] + bb[j])};
                *(bf16x4*)&o16[((size_t)(bidx * H_ + head) * DM_ + dmb + j) * T_ + t] = u;
            }
    }
}

// ---------------------------------------------------------------------------
// out-projection GEMM (fp32 out), 64x128 tile, gload_lds dbuf staging.
// ---------------------------------------------------------------------------
__global__ __launch_bounds__(256)
void mgemm_out_kernel(const unsigned short* __restrict__ A,
                      const unsigned short* __restrict__ Bt,
                      const float* __restrict__ bias, float* __restrict__ out,
                      int M, int N, int K)
{
    __shared__ __align__(16) unsigned short Al[2][64 * 64];
    __shared__ __align__(16) unsigned short Bl[2][128 * 64];

    const int tid = threadIdx.x;
    const int w  = tid >> 6, l = tid & 63;
    const int lo = l & 15,  g = l >> 4;
    const int wri = w >> 1, wci = w & 1;
    const int m0 = blockIdx.y * 64, n0 = blockIdx.x * 128;
    const int lrow = l >> 3;
    const int lslot = (l & 7) ^ lrow;

    f32x4 acc[2][4] = {};
    const int nk = K >> 6;

#pragma unroll
    for (int p = 0; p < 2; ++p) {
        int br = w * 16 + p * 8;
        GLOAD16(A + (size_t)(m0 + br + lrow) * K + lslot * 8, (char*)Al[0] + br * 128);
    }
#pragma unroll
    for (int p = 0; p < 4; ++p) {
        int br = w * 32 + p * 8;
        GLOAD16(Bt + (size_t)(n0 + br + lrow) * K + lslot * 8, (char*)Bl[0] + br * 128);
    }
    __syncthreads();

    for (int t = 0; t < nk; ++t) {
        const int cur = t & 1;
        if (t + 1 < nk) {
            const int k0 = (t + 1) << 6;
#pragma unroll
            for (int p = 0; p < 2; ++p) {
                int br = w * 16 + p * 8;
                GLOAD16(A + (size_t)(m0 + br + lrow) * K + k0 + lslot * 8,
                        (char*)Al[cur ^ 1] + br * 128);
            }
#pragma unroll
            for (int p = 0; p < 4; ++p) {
                int br = w * 32 + p * 8;
                GLOAD16(Bt + (size_t)(n0 + br + lrow) * K + k0 + lslot * 8,
                        (char*)Bl[cur ^ 1] + br * 128);
            }
        }
#pragma unroll
        for (int kk = 0; kk < 2; ++kk) {
            bf16x8 af[2], bfr[4];
#pragma unroll
            for (int i = 0; i < 2; ++i) {
                int row = wri * 32 + i * 16 + lo;
                af[i] = *(const bf16x8*)&Al[cur][row * 64 + ((((kk << 2) + g) ^ (row & 7)) << 3)];
            }
#pragma unroll
            for (int j = 0; j < 4; ++j) {
                int col = wci * 64 + j * 16 + lo;
                bfr[j] = *(const bf16x8*)&Bl[cur][col * 64 + ((((kk << 2) + g) ^ (col & 7)) << 3)];
            }
#pragma unroll
            for (int i = 0; i < 2; ++i)
#pragma unroll
                for (int j = 0; j < 4; ++j)
                    acc[i][j] = __builtin_amdgcn_mfma_f32_16x16x32_bf16(af[i], bfr[j], acc[i][j], 0, 0, 0);
        }
        __syncthreads();
    }

    const int mb = m0 + wri * 32 + g * 4;
#pragma unroll
    for (int j = 0; j < 4; ++j) {
        int n = n0 + wci * 64 + j * 16 + lo;
        float bb = bias[n];
#pragma unroll
        for (int i = 0; i < 2; ++i)
#pragma unroll
            for (int jj = 0; jj < 4; ++jj) {
                int m = mb + i * 16 + jj;
                out[(size_t)m * N + n] = acc[i][j][jj] + bb;
            }
    }
}

// ---------------------------------------------------------------------------
// MFMA flash attention v12: 4 waves x 32 q, mfma_32x32x16 (2x FLOP per LDS
// byte vs 16x16x32), P kept in REGISTERS (cvt_pk + shfl_xor(32) half-
// exchange -- no P LDS round trip), SM(t)||PV(t-1) pipeline, K dbuf,
// V tri-buf, no-max softmax, pad bias as MFMA C-init, XCD-aware grid.
//
// Layouts (m74-verified): mfma_32x32x16 A: row=l&31, k=(l>>5)*8+i.
// C: col=l&31 (=q), row=(reg&3)+8*(reg>>2)+4*(l>>5) (=key/d).
// Lane (q=l&31, h=l>>5) owns keys with (key mod 8) in [4h,4h+4).
// PV B-frag(kc) needs keys 16kc+8h..+7: own window quad + partner's quad
// of window w*=2kc+h; send window 2kc+1-h, recv = partner's 2kc+h.
// ---------------------------------------------------------------------------
__global__ __launch_bounds__(256, 2)
void attn_kernel(const unsigned short* __restrict__ Qh,
                 const unsigned short* __restrict__ Kh,
                 const unsigned short* __restrict__ Vt,
                 const float* __restrict__ padb,
                 unsigned short* __restrict__ ctx)
{
    __shared__ __align__(16) unsigned short Ks[2][64 * 64];      // 16KB
    __shared__ __align__(16) unsigned short Vs[3][64 * 64];      // 24KB
    __shared__ __align__(16) float pbs[T_];                      // 8KB

    const int tid  = threadIdx.x;
    const int w    = tid >> 6;        // 0..3
    const int l    = tid & 63;
    const int rowa = l & 31;
    const int h    = l >> 5;          // 0/1
    const int h4   = h * 4;
    const int lrow = l >> 3;          // 0..7
    const int lslot = (l & 7) ^ lrow; // pre-swizzled source slot

    // XCD-aware decode: blocks of one head cluster on one XCD's L2.
    const int f   = blockIdx.x;
    const int s   = f >> 3;
    const int bh  = (f & 7) * 4 + (s >> 4);
    const int q0  = (s & 15) * 128;
    const int bb  = bh >> 4;
    const int hh  = bh & 15;

    // Q frags: B-operand of QK. qf[kq] = Q[q][kq*16 + 8h .. +8]
    bf16x8 qf[4];
    {
        const unsigned short* Qp =
            Qh + ((size_t)bh * T_ + q0 + w * 32 + rowa) * DM_ + h * 8;
#pragma unroll
        for (int kq = 0; kq < 4; ++kq) qf[kq] = *(const bf16x8*)(Qp + kq * 16);
    }

    // staging source pointers
    const unsigned short* kgp =
        Kh + (size_t)bh * T_ * DM_ + (size_t)(w * 16 + lrow) * DM_ + lslot * 8;
    const unsigned short* vgp =
        Vt + (size_t)bh * DM_ * T_ + (size_t)(w * 16 + lrow) * T_ + lslot * 8;

    // pad-bias table -> LDS (2048 floats / 256 thr = 8 each)
    {
        const float* src = padb + bb * T_ + tid * 8;
        *(float4*)&pbs[tid * 8]     = *(const float4*)(src);
        *(float4*)&pbs[tid * 8 + 4] = *(const float4*)(src + 4);
    }

    // stage tile 0 -> Ks[0], Vs[0]: wave w rows w*16..+15 (2 GLOADs each)
    GLOAD16(kgp,            (char*)Ks[0] + w * 2048);
    GLOAD16(kgp + 8 * DM_,  (char*)Ks[0] + w * 2048 + 1024);
    GLOAD16(vgp,            (char*)Vs[0] + w * 2048);
    GLOAD16(vgp + 8 * T_,   (char*)Vs[0] + w * 2048 + 1024);
    kgp += 64 * DM_;
    vgp += 64;

    // per-lane LDS read offsets: row = kb*32 + rowa, slot (2k+h)^(row&7)
    const int kbase = rowa * 128;
    const int sw = rowa & 7;
    int e[4];
#pragma unroll
    for (int i = 0; i < 4; ++i) e[i] = (((2 * i + h) ^ sw) << 4);

    __syncthreads();

    f32x16 oa0 = {}, oa1 = {};
    float lsum = 0.f;
    bf16x8 pA[4], pB[4];
    const float* pbp = pbs;

    char* Kc = (char*)Ks[0];
    char* Kw = (char*)Ks[1];
    char* Vr = (char*)Vs[2];
    char* Vn = (char*)Vs[0];
    char* Vw = (char*)Vs[1];

#define QK_SM(PW, DO_STAGE, DO_PV, PR)                                        \
    {                                                                         \
        if (DO_STAGE) {                                                       \
            GLOAD16(kgp,           Kw + w * 2048);                            \
            GLOAD16(kgp + 8 * DM_, Kw + w * 2048 + 1024);                     \
            GLOAD16(vgp,           Vw + w * 2048);                            \
            GLOAD16(vgp + 8 * T_,  Vw + w * 2048 + 1024);                     \
            kgp += 64 * DM_;                                                  \
            vgp += 64;                                                        \
        }                                                                     \
        f32x16 sa0, sa1;                                                      \
        _Pragma("unroll")                                                     \
        for (int m = 0; m < 4; ++m) {                                         \
            f32x4 b0 = *(const f32x4*)(pbp + m * 8 + h4);                     \
            f32x4 b1 = *(const f32x4*)(pbp + 32 + m * 8 + h4);                \
            sa0[4*m+0] = b0[0]; sa0[4*m+1] = b0[1];                           \
            sa0[4*m+2] = b0[2]; sa0[4*m+3] = b0[3];                           \
            sa1[4*m+0] = b1[0]; sa1[4*m+1] = b1[1];                           \
            sa1[4*m+2] = b1[2]; sa1[4*m+3] = b1[3];                           \
        }                                                                     \
        __builtin_amdgcn_s_setprio(1);                                        \
        _Pragma("unroll")                                                     \
        for (int kq = 0; kq < 4; ++kq) {                                      \
            bf16x8 k0 = *(const bf16x8*)(Kc + kbase + e[kq]);                 \
            bf16x8 k1 = *(const bf16x8*)(Kc + kbase + 4096 + e[kq]);          \
            sa0 = __builtin_amdgcn_mfma_f32_32x32x16_bf16(k0, qf[kq], sa0, 0, 0, 0); \
            sa1 = __builtin_amdgcn_mfma_f32_32x32x16_bf16(k1, qf[kq], sa1, 0, 0, 0); \
        }                                                                     \
        __builtin_amdgcn_s_setprio(0);                                        \
        bf16x8 vf0[4], vf1[4];                                                \
        if (DO_PV) {                                                          \
            _Pragma("unroll")                                                 \
            for (int kc = 0; kc < 4; ++kc) {                                  \
                vf0[kc] = *(const bf16x8*)(Vr + kbase + e[kc]);               \
                vf1[kc] = *(const bf16x8*)(Vr + kbase + 4096 + e[kc]);        \
            }                                                                 \
        }                                                                     \
        u32 qlo[8], qhi[8];                                                   \
        _Pragma("unroll")                                                     \
        for (int m = 0; m < 4; ++m) {                                         \
            float e0 = EXP2(sa0[4*m+0]), e1 = EXP2(sa0[4*m+1]);               \
            float e2 = EXP2(sa0[4*m+2]), e3 = EXP2(sa0[4*m+3]);               \
            lsum += (e0 + e1) + (e2 + e3);                                    \
            qlo[m] = pack2bf(e0, e1); qhi[m] = pack2bf(e2, e3);               \
            float f0 = EXP2(sa1[4*m+0]), f1 = EXP2(sa1[4*m+1]);               \
            float f2 = EXP2(sa1[4*m+2]), f3 = EXP2(sa1[4*m+3]);               \
            lsum += (f0 + f1) + (f2 + f3);                                    \
            qlo[4+m] = pack2bf(f0, f1); qhi[4+m] = pack2bf(f2, f3);           \
        }                                                                     \
        _Pragma("unroll")                                                     \
        for (int kc = 0; kc < 4; ++kc) {                                      \
            u32 a_lo = h ? qlo[2*kc] : qlo[2*kc+1];                           \
            u32 a_hi = h ? qhi[2*kc] : qhi[2*kc+1];                           \
            u32 o_lo = h ? qlo[2*kc+1] : qlo[2*kc];                           \
            u32 o_hi = h ? qhi[2*kc+1] : qhi[2*kc];                           \
            u32 r_lo = (u32)__shfl_xor((int)a_lo, 32);                        \
            u32 r_hi = (u32)__shfl_xor((int)a_hi, 32);                        \
            uint4 uu;                                                         \
            uu.x = h ? r_lo : o_lo; uu.y = h ? r_hi : o_hi;                   \
            uu.z = h ? o_lo : r_lo; uu.w = h ? o_hi : r_hi;                   \
            PW[kc] = *(bf16x8*)&uu;                                           \
        }                                                                     \
        if (DO_PV) {                                                          \
            __builtin_amdgcn_s_setprio(1);                                    \
            _Pragma("unroll")                                                 \
            for (int kc = 0; kc < 4; ++kc) {                                  \
                oa0 = __builtin_amdgcn_mfma_f32_32x32x16_bf16(vf0[kc], PR[kc], oa0, 0, 0, 0); \
                oa1 = __builtin_amdgcn_mfma_f32_32x32x16_bf16(vf1[kc], PR[kc], oa1, 0, 0, 0); \
            }                                                                 \
            __builtin_amdgcn_s_setprio(0);                                    \
        }                                                                     \
        pbp += 64;                                                            \
        __syncthreads();                                                      \
        { char* tk = Kc; Kc = Kw; Kw = tk;                                    \
          char* tv = Vr; Vr = Vn; Vn = Vw; Vw = tv; }                         \
    }

    // peel t=0: stage(1), QK(0)+SM(0) -> pA, no PV
    QK_SM(pA, true, false, pB)

    // t = 1..30 in unrolled pairs (P register double-buffer via role swap)
    for (int it = 1; it < NT_ - 1; it += 2) {
        QK_SM(pB, true, true, pA)                 // odd t: read pA, write pB
        QK_SM(pA, (it + 2 < NT_), true, pB)       // even t: read pB, write pA
    }
    // t = 31: read pA (=P30), write pB (=P31), no stage
    QK_SM(pB, false, true, pA)

    // final PV(31): Vr = V(31) after last rotation, P in pB
    {
#pragma unroll
        for (int kc = 0; kc < 4; ++kc) {
            bf16x8 v0 = *(const bf16x8*)(Vr + kbase + e[kc]);
            bf16x8 v1 = *(const bf16x8*)(Vr + kbase + 4096 + e[kc]);
            oa0 = __builtin_amdgcn_mfma_f32_32x32x16_bf16(v0, pB[kc], oa0, 0, 0, 0);
            oa1 = __builtin_amdgcn_mfma_f32_32x32x16_bf16(v1, pB[kc], oa1, 0, 0, 0);
        }
    }
#undef QK_SM

    // ---- l reduce (partner lane holds other 32 keys of same q) + ctx write
    float lt = lsum + __shfl_xor(lsum, 32);
    float linv = 1.0f / lt;
    const size_t crow =
        ((size_t)(bb * T_ + q0 + w * 32 + rowa)) * NQ_ + hh * DM_;
#pragma unroll
    for (int m = 0; m < 4; ++m) {
        bf16x4 u0 = {bfc(oa0[4*m+0] * linv), bfc(oa0[4*m+1] * linv),
                     bfc(oa0[4*m+2] * linv), bfc(oa0[4*m+3] * linv)};
        *(bf16x4*)&ctx[crow + 8 * m + h4] = u0;
        bf16x4 u1 = {bfc(oa1[4*m+0] * linv), bfc(oa1[4*m+1] * linv),
                     bfc(oa1[4*m+2] * linv), bfc(oa1[4*m+3] * linv)};
        *(bf16x4*)&ctx[crow + 32 + 8 * m + h4] = u1;
    }
}

// ---------------------------------------------------------------------------
extern "C" void kernel_launch(void* const* d_in, const int* in_sizes, int n_in,
                              void* d_out, int out_size, void* d_ws, size_t ws_size,
                              hipStream_t stream) {
    const float* data = (const float*)d_in[0];
    const float* mask = (const float*)d_in[1];
    const float* wq   = (const float*)d_in[2];
    const float* bq   = (const float*)d_in[3];
    const float* wk   = (const float*)d_in[4];
    const float* bk   = (const float*)d_in[5];
    const float* wv   = (const float*)d_in[6];
    const float* bv   = (const float*)d_in[7];
    const float* wo   = (const float*)d_in[8];
    const float* bo   = (const float*)d_in[9];
    float* out = (float*)d_out;

    char* ws = (char*)d_ws;
    const size_t MB = 1024 * 1024;
    unsigned short* Qh    = (unsigned short*)(ws);             // 8MB
    unsigned short* Kh    = (unsigned short*)(ws +  8 * MB);   // 8MB
    unsigned short* Vt    = (unsigned short*)(ws + 16 * MB);   // 8MB
    unsigned short* CTX   = (unsigned short*)(ws + 24 * MB);   // 8MB (bf16)
    unsigned short* dataB = (unsigned short*)(ws + 32 * MB);   // 4MB
    unsigned short* BtAll = (unsigned short*)(ws + 36 * MB);   // 3MB
    unsigned short* wot   = (unsigned short*)(ws + 39 * MB);   // 1MB
    float*          padb  = (float*)         (ws + 40 * MB);   // 16KB

    const int M = B_ * T_;                 // 4096
    const float alpha_q = 0.125f * 1.44269504089f;

    prep_kernel<<<4096, 256, 0, stream>>>(mask, padb, data, dataB,
                                          wq, wk, wv, BtAll, wo, wot);

    mgemm_qkv_kernel<<<dim3(3 * NQ_ / 128, M / 128), 256, 0, stream>>>(
        dataB, BtAll, bq, bk, bv, Qh, Kh, Vt, alpha_q);

    attn_kernel<<<512, 256, 0, stream>>>(Qh, Kh, Vt, padb, CTX);

    mgemm_out_kernel<<<dim3(D_ / 128, M / 64), 256, 0, stream>>>(
        CTX, wot, bo, out, M, D_, NQ_);
}

// Round 13
// 109.229 us; speedup vs baseline: 1.0440x; 1.0440x over previous
//
#include <hip/hip_runtime.h>
#include <hip/hip_bf16.h>

#define B_  2
#define T_  2048
#define D_  512
#define DM_ 64
#define H_  16
#define NQ_ (DM_*H_)   // 1024
#define NT_ (T_/64)    // 32 key tiles

typedef __bf16 bf16x8 __attribute__((ext_vector_type(8)));
typedef __bf16 bf16x4 __attribute__((ext_vector_type(4)));
typedef float  f32x4  __attribute__((ext_vector_type(4)));
typedef unsigned int u32;

static __device__ __forceinline__ __bf16 bfc(float x) { return (__bf16)x; }
static __device__ __forceinline__ unsigned short f2bf(float x) {
    __bf16 b = (__bf16)x;
    unsigned short u;
    __builtin_memcpy(&u, &b, 2);
    return u;
}

#if __has_builtin(__builtin_amdgcn_exp2f)
static __device__ __forceinline__ float EXP2(float x) { return __builtin_amdgcn_exp2f(x); }
#else
static __device__ __forceinline__ float EXP2(float x) {
    float r; asm("v_exp_f32 %0, %1\ns_nop 0" : "=v"(r) : "v"(x)); return r;
}
#endif

// async global->LDS, 16B per lane; dest = wave-uniform base + lane*16
#define GLOAD16(gp, lp) \
    __builtin_amdgcn_global_load_lds((const __attribute__((address_space(1))) u32*)(gp), \
                                     (__attribute__((address_space(3))) u32*)(lp), 16, 0, 0)

// ---------------------------------------------------------------------------
// fused prep: [0,1024) pad | [1024,2048) data cvt | [2048,3584) qkv wtrans |
// [3584,4096) wo wtrans
// ---------------------------------------------------------------------------
__global__ __launch_bounds__(256)
void prep_kernel(const float* __restrict__ mask, float* __restrict__ padb,
                 const float* __restrict__ data, unsigned short* __restrict__ dataB,
                 const float* __restrict__ wq, const float* __restrict__ wk,
                 const float* __restrict__ wv, unsigned short* __restrict__ btall,
                 const float* __restrict__ wo, unsigned short* __restrict__ wot)
{
    __shared__ float t[32][33];
    const int bid = blockIdx.x;
    const int tid = threadIdx.x;
    if (bid < 1024) {
        const int row  = bid * 4 + (tid >> 6);
        const int lane = tid & 63;
        const float* p = mask + (size_t)row * D_;
        float4 a = *(const float4*)&p[lane * 8];
        float4 b = *(const float4*)&p[lane * 8 + 4];
        float s = a.x + a.y + a.z + a.w + b.x + b.y + b.z + b.w;
#pragma unroll
        for (int off = 32; off; off >>= 1) s += __shfl_down(s, off);
        if (lane == 0) padb[row] = (s == 0.0f) ? -1e9f : 0.0f;
    } else if (bid < 2048) {
        int i = ((bid - 1024) * 256 + tid) * 8;
        float4 a = *(const float4*)&data[i];
        float4 b = *(const float4*)&data[i + 4];
        bf16x8 u = {bfc(a.x), bfc(a.y), bfc(a.z), bfc(a.w),
                    bfc(b.x), bfc(b.y), bfc(b.z), bfc(b.w)};
        *(bf16x8*)&dataB[i] = u;
    } else if (bid < 3584) {
        const int idx = bid - 2048;
        const int z = idx >> 9, rem = idx & 511;
        const int c0 = (rem & 31) * 32, r0 = (rem >> 5) * 32;   // C=1024, R=512
        const float* in = (z == 0) ? wq : (z == 1) ? wk : wv;
        unsigned short* out = btall + (size_t)z * NQ_ * D_;
        const int tx = tid & 31, ty = tid >> 5;
#pragma unroll
        for (int i = 0; i < 4; ++i)
            t[ty * 4 + i][tx] = in[(size_t)(r0 + ty * 4 + i) * NQ_ + c0 + tx];
        __syncthreads();
#pragma unroll
        for (int i = 0; i < 4; ++i)
            out[(size_t)(c0 + ty * 4 + i) * D_ + r0 + tx] = f2bf(t[tx][ty * 4 + i]);
    } else {
        const int idx = bid - 3584;
        const int c0 = (idx & 15) * 32, r0 = (idx >> 4) * 32;   // C=512, R=1024
        const int tx = tid & 31, ty = tid >> 5;
#pragma unroll
        for (int i = 0; i < 4; ++i)
            t[ty * 4 + i][tx] = wo[(size_t)(r0 + ty * 4 + i) * D_ + c0 + tx];
        __syncthreads();
#pragma unroll
        for (int i = 0; i < 4; ++i)
            wot[(size_t)(c0 + ty * 4 + i) * NQ_ + r0 + tx] = f2bf(t[tx][ty * 4 + i]);
    }
}

// ---------------------------------------------------------------------------
// fused QKV GEMM: A[4096,512] @ BtAll[3072,512]^T, gload_lds dbuf staging.
// seg 0 -> Qh head-major *alpha_q, 1 -> Kh head-major, 2 -> Vt transposed.
// ---------------------------------------------------------------------------
__global__ __launch_bounds__(256)
void mgemm_qkv_kernel(const unsigned short* __restrict__ A,
                      const unsigned short* __restrict__ BtAll,
                      const float* __restrict__ bq, const float* __restrict__ bk,
                      const float* __restrict__ bv,
                      unsigned short* __restrict__ Qh, unsigned short* __restrict__ Kh,
                      unsigned short* __restrict__ Vt, float alpha_q)
{
    const int K = D_;
    __shared__ __align__(16) unsigned short Al[2][128 * 64];
    __shared__ __align__(16) unsigned short Bl[2][128 * 64];

    const int tid = threadIdx.x;
    const int w  = tid >> 6, l = tid & 63;
    const int lo = l & 15,  g = l >> 4;
    const int wri = w >> 1, wci = w & 1;
    const int m0 = blockIdx.y * 128, n0 = blockIdx.x * 128;
    const int lrow = l >> 3;
    const int lslot = (l & 7) ^ lrow;     // pre-swizzled source slot

    f32x4 acc[4][4] = {};
    const int nk = K >> 6;   // 8

    // prologue: stage k-step 0 into buf0
#pragma unroll
    for (int p = 0; p < 4; ++p) {
        int br = w * 32 + p * 8;
        GLOAD16(A     + (size_t)(m0 + br + lrow) * K + lslot * 8, (char*)Al[0] + br * 128);
        GLOAD16(BtAll + (size_t)(n0 + br + lrow) * K + lslot * 8, (char*)Bl[0] + br * 128);
    }
    __syncthreads();

    for (int t = 0; t < nk; ++t) {
        const int cur = t & 1;
        if (t + 1 < nk) {
            const int k0 = (t + 1) << 6;
#pragma unroll
            for (int p = 0; p < 4; ++p) {
                int br = w * 32 + p * 8;
                GLOAD16(A     + (size_t)(m0 + br + lrow) * K + k0 + lslot * 8,
                        (char*)Al[cur ^ 1] + br * 128);
                GLOAD16(BtAll + (size_t)(n0 + br + lrow) * K + k0 + lslot * 8,
                        (char*)Bl[cur ^ 1] + br * 128);
            }
        }
#pragma unroll
        for (int kk = 0; kk < 2; ++kk) {
            bf16x8 af[4], bfr[4];
#pragma unroll
            for (int i = 0; i < 4; ++i) {
                int row = wri * 64 + i * 16 + lo;
                af[i] = *(const bf16x8*)&Al[cur][row * 64 + ((((kk << 2) + g) ^ (row & 7)) << 3)];
                int col = wci * 64 + i * 16 + lo;
                bfr[i] = *(const bf16x8*)&Bl[cur][col * 64 + ((((kk << 2) + g) ^ (col & 7)) << 3)];
            }
#pragma unroll
            for (int i = 0; i < 4; ++i)
#pragma unroll
                for (int j = 0; j < 4; ++j)
                    acc[i][j] = __builtin_amdgcn_mfma_f32_16x16x32_bf16(af[i], bfr[j], acc[i][j], 0, 0, 0);
        }
        __syncthreads();
    }

    const int seg = n0 >> 10;                  // 0:Q 1:K 2:V
    const int n0l = n0 & 1023;
    const float* bias = (seg == 0) ? bq : (seg == 1) ? bk : bv;
    const float alpha = (seg == 0) ? alpha_q : 1.0f;
    unsigned short* o16 = (seg == 0) ? Qh : (seg == 1) ? Kh : Vt;

    const int mb = m0 + wri * 64 + g * 4;
    float bb[4];
#pragma unroll
    for (int j = 0; j < 4; ++j) bb[j] = bias[n0l + wci * 64 + j * 16 + lo];
    const int head = lo;
    const int dmb  = (n0l >> 4) + wci * 4;
    if (seg < 2) {
#pragma unroll
        for (int i = 0; i < 4; ++i)
#pragma unroll
            for (int jj = 0; jj < 4; ++jj) {
                int m = mb + i * 16 + jj;
                int t = m & (T_ - 1), bidx = m >> 11;
                bf16x4 u = {bfc((acc[i][0][jj] + bb[0]) * alpha),
                            bfc((acc[i][1][jj] + bb[1]) * alpha),
                            bfc((acc[i][2][jj] + bb[2]) * alpha),
                            bfc((acc[i][3][jj] + bb[3]) * alpha)};
                *(bf16x4*)&o16[(((size_t)(bidx * H_ + head)) * T_ + t) * DM_ + dmb] = u;
            }
    } else {
#pragma unroll
        for (int i = 0; i < 4; ++i)
#pragma unroll
            for (int j = 0; j < 4; ++j) {
                int m = mb + i * 16;
                int t = m & (T_ - 1), bidx = m >> 11;
                bf16x4 u = {bfc(acc[i][j][0] + bb[j]), bfc(acc[i][j][1] + bb[j]),
                            bfc(acc[i][j][2] + bb[j]), bfc(acc[i][j][3] + bb[j])};
                *(bf16x4*)&o16[((size_t)(bidx * H_ + head) * DM_ + dmb + j) * T_ + t] = u;
            }
    }
}

// ---------------------------------------------------------------------------
// out-projection GEMM (fp32 out), 64x128 tile, gload_lds dbuf staging.
// ---------------------------------------------------------------------------
__global__ __launch_bounds__(256)
void mgemm_out_kernel(const unsigned short* __restrict__ A,
                      const unsigned short* __restrict__ Bt,
                      const float* __restrict__ bias, float* __restrict__ out,
                      int M, int N, int K)
{
    __shared__ __align__(16) unsigned short Al[2][64 * 64];
    __shared__ __align__(16) unsigned short Bl[2][128 * 64];

    const int tid = threadIdx.x;
    const int w  = tid >> 6, l = tid & 63;
    const int lo = l & 15,  g = l >> 4;
    const int wri = w >> 1, wci = w & 1;
    const int m0 = blockIdx.y * 64, n0 = blockIdx.x * 128;
    const int lrow = l >> 3;
    const int lslot = (l & 7) ^ lrow;

    f32x4 acc[2][4] = {};
    const int nk = K >> 6;

#pragma unroll
    for (int p = 0; p < 2; ++p) {
        int br = w * 16 + p * 8;
        GLOAD16(A + (size_t)(m0 + br + lrow) * K + lslot * 8, (char*)Al[0] + br * 128);
    }
#pragma unroll
    for (int p = 0; p < 4; ++p) {
        int br = w * 32 + p * 8;
        GLOAD16(Bt + (size_t)(n0 + br + lrow) * K + lslot * 8, (char*)Bl[0] + br * 128);
    }
    __syncthreads();

    for (int t = 0; t < nk; ++t) {
        const int cur = t & 1;
        if (t + 1 < nk) {
            const int k0 = (t + 1) << 6;
#pragma unroll
            for (int p = 0; p < 2; ++p) {
                int br = w * 16 + p * 8;
                GLOAD16(A + (size_t)(m0 + br + lrow) * K + k0 + lslot * 8,
                        (char*)Al[cur ^ 1] + br * 128);
            }
#pragma unroll
            for (int p = 0; p < 4; ++p) {
                int br = w * 32 + p * 8;
                GLOAD16(Bt + (size_t)(n0 + br + lrow) * K + k0 + lslot * 8,
                        (char*)Bl[cur ^ 1] + br * 128);
            }
        }
#pragma unroll
        for (int kk = 0; kk < 2; ++kk) {
            bf16x8 af[2], bfr[4];
#pragma unroll
            for (int i = 0; i < 2; ++i) {
                int row = wri * 32 + i * 16 + lo;
                af[i] = *(const bf16x8*)&Al[cur][row * 64 + ((((kk << 2) + g) ^ (row & 7)) << 3)];
            }
#pragma unroll
            for (int j = 0; j < 4; ++j) {
                int col = wci * 64 + j * 16 + lo;
                bfr[j] = *(const bf16x8*)&Bl[cur][col * 64 + ((((kk << 2) + g) ^ (col & 7)) << 3)];
            }
#pragma unroll
            for (int i = 0; i < 2; ++i)
#pragma unroll
                for (int j = 0; j < 4; ++j)
                    acc[i][j] = __builtin_amdgcn_mfma_f32_16x16x32_bf16(af[i], bfr[j], acc[i][j], 0, 0, 0);
        }
        __syncthreads();
    }

    const int mb = m0 + wri * 32 + g * 4;
#pragma unroll
    for (int j = 0; j < 4; ++j) {
        int n = n0 + wci * 64 + j * 16 + lo;
        float bb = bias[n];
#pragma unroll
        for (int i = 0; i < 2; ++i)
#pragma unroll
            for (int jj = 0; jj < 4; ++jj) {
                int m = mb + i * 16 + jj;
                out[(size_t)m * N + n] = acc[i][j][jj] + bb;
            }
    }
}

// ---------------------------------------------------------------------------
// MFMA flash attention v13 = R9 geometry (4 waves x 32 q: half the LDS
// traffic per q-row) + R11 pipeline (SM(t) || PV(t-1), K dbuf, V tri-buf,
// P LDS dbuf, PV operands preloaded before SM) + pbs in LDS.
// 16x16x32 MFMA, conflict-free swizzle, no-max softmax, XCD-aware grid.
// LDS 80KB -> 2 blocks/CU; pipeline supplies ILP that 2 waves/SIMD lack.
// ---------------------------------------------------------------------------
__global__ __launch_bounds__(256, 2)
void attn_kernel(const unsigned short* __restrict__ Qh,
                 const unsigned short* __restrict__ Kh,
                 const unsigned short* __restrict__ Vt,
                 const float* __restrict__ padb,
                 unsigned short* __restrict__ ctx)
{
    __shared__ __align__(16) unsigned short Ks[2][64 * 64];      // 16KB
    __shared__ __align__(16) unsigned short Vs[3][64 * 64];      // 24KB
    __shared__ __align__(16) unsigned short Ps[4][2][32 * 64];   // 32KB
    __shared__ __align__(16) float pbs[T_];                      // 8KB

    const int tid  = threadIdx.x;
    const int w    = tid >> 6;        // 0..3
    const int l    = tid & 63;
    const int lo16 = l & 15;
    const int g    = l >> 4;
    const int lrow = l >> 3;          // 0..7
    const int lslot = (l & 7) ^ lrow; // pre-swizzled source slot

    // XCD-aware decode: blocks of one head cluster on one XCD's L2.
    const int f   = blockIdx.x;
    const int s   = f >> 3;
    const int bh  = (f & 7) * 4 + (s >> 4);
    const int q0  = (s & 15) * 128;
    const int bb  = bh >> 4;
    const int hh  = bh & 15;

    bf16x8 qf[2][2];
#pragma unroll
    for (int qt = 0; qt < 2; ++qt) {
        const unsigned short* Qp =
            Qh + ((size_t)bh * T_ + q0 + w * 32 + qt * 16 + lo16) * DM_ + g * 8;
        qf[qt][0] = *(const bf16x8*)(Qp);
        qf[qt][1] = *(const bf16x8*)(Qp + 32);
    }

    // staging source pointers (strength-reduced per iteration)
    const unsigned short* kgp =
        Kh + (size_t)bh * T_ * DM_ + (size_t)(w * 16 + lrow) * DM_ + lslot * 8;
    const unsigned short* vgp =
        Vt + (size_t)bh * DM_ * T_ + (size_t)(w * 16 + lrow) * T_ + lslot * 8;

    // pad-bias table -> LDS once (2048 floats / 256 thr = 8 each)
    {
        const float* src = padb + bb * T_ + tid * 8;
        *(float4*)&pbs[tid * 8]     = *(const float4*)(src);
        *(float4*)&pbs[tid * 8 + 4] = *(const float4*)(src + 4);
    }

    // stage tile 0 -> Ks[0], Vs[0]: wave w rows w*16..+15 (2 GLOADs each)
    GLOAD16(kgp,           (char*)Ks[0] + (w * 16) * 128);
    GLOAD16(kgp + 8 * DM_, (char*)Ks[0] + (w * 16 + 8) * 128);
    GLOAD16(vgp,           (char*)Vs[0] + (w * 16) * 128);
    GLOAD16(vgp + 8 * T_,  (char*)Vs[0] + (w * 16 + 8) * 128);
    kgp += 64 * DM_;
    vgp += 64;

    const int rswz = (lo16 & 7) << 4;
    __syncthreads();

    f32x4 oa[2][4] = {};
    f32x4 ls4[2] = {};
    const float* pbp = pbs;

    // rotating buffer pointers (named, no runtime indexing)
    char* Kc = (char*)Ks[0];          // K(t) read
    char* Kw = (char*)Ks[1];          // K(t+1) staging target
    char* Vr = (char*)Vs[2];          // V(t-1) read (unused at t=0)
    char* Vn = (char*)Vs[0];          // V(t)   (idle this iter)
    char* Vw = (char*)Vs[1];          // V(t+1) staging target
    char* Pc = (char*)&Ps[w][0][0];   // P(t) write
    char* Pp = (char*)&Ps[w][1][0];   // P(t-1) read

    // ---------------- peeled iteration 0: stage(1); QK(0); SM(0) ----------
    {
        GLOAD16(kgp,           Kw + (w * 16) * 128);
        GLOAD16(kgp + 8 * DM_, Kw + (w * 16 + 8) * 128);
        GLOAD16(vgp,           Vw + (w * 16) * 128);
        GLOAD16(vgp + 8 * T_,  Vw + (w * 16 + 8) * 128);
        kgp += 64 * DM_;
        vgp += 64;

        f32x4 sa[2][4];
#pragma unroll
        for (int nt = 0; nt < 4; ++nt) {
            f32x4 pb4 = *(const f32x4*)&pbp[nt * 16 + g * 4];
            sa[0][nt] = pb4;
            sa[1][nt] = pb4;
        }
        __builtin_amdgcn_s_setprio(1);
#pragma unroll
        for (int ks = 0; ks < 2; ++ks) {
#pragma unroll
            for (int nt = 0; nt < 4; ++nt) {
                int row = nt * 16 + lo16;
                int off = (row * 128 + ks * 64 + g * 16) ^ ((row & 7) << 4);
                bf16x8 kf = *(const bf16x8*)(Kc + off);
#pragma unroll
                for (int qt = 0; qt < 2; ++qt)
                    sa[qt][nt] = __builtin_amdgcn_mfma_f32_16x16x32_bf16(kf, qf[qt][ks], sa[qt][nt], 0, 0, 0);
            }
        }
        __builtin_amdgcn_s_setprio(0);
#pragma unroll
        for (int qt = 0; qt < 2; ++qt) {
            const int prow = qt * 16 + lo16;
#pragma unroll
            for (int nt = 0; nt < 4; ++nt) {
                float e0 = EXP2(sa[qt][nt][0]);
                float e1 = EXP2(sa[qt][nt][1]);
                float e2 = EXP2(sa[qt][nt][2]);
                float e3 = EXP2(sa[qt][nt][3]);
                ls4[qt] += (f32x4){e0, e1, e2, e3};
                bf16x4 p4 = {bfc(e0), bfc(e1), bfc(e2), bfc(e3)};
                int wb = (prow * 128 + nt * 32 + g * 8) ^ rswz;
                *(bf16x4*)(Pc + wb) = p4;
            }
        }
        pbp += 64;
        __syncthreads();
        { char* tk = Kc; Kc = Kw; Kw = tk;
          char* tv = Vr; Vr = Vn; Vn = Vw; Vw = tv;
          char* tp = Pc; Pc = Pp; Pp = tp; }
    }

    // ---------------- main loop: t = 1 .. NT-1 -----------------------------
    for (int it = 1; it < NT_; ++it) {
        if (it + 1 < NT_) {
            GLOAD16(kgp,           Kw + (w * 16) * 128);
            GLOAD16(kgp + 8 * DM_, Kw + (w * 16 + 8) * 128);
            GLOAD16(vgp,           Vw + (w * 16) * 128);
            GLOAD16(vgp + 8 * T_,  Vw + (w * 16 + 8) * 128);
            kgp += 64 * DM_;
            vgp += 64;
        }

        // QK(t): C-init = pad bias from LDS
        f32x4 sa[2][4];
#pragma unroll
        for (int nt = 0; nt < 4; ++nt) {
            f32x4 pb4 = *(const f32x4*)&pbp[nt * 16 + g * 4];
            sa[0][nt] = pb4;
            sa[1][nt] = pb4;
        }
        __builtin_amdgcn_s_setprio(1);
#pragma unroll
        for (int ks = 0; ks < 2; ++ks) {
#pragma unroll
            for (int nt = 0; nt < 4; ++nt) {
                int row = nt * 16 + lo16;
                int off = (row * 128 + ks * 64 + g * 16) ^ ((row & 7) << 4);
                bf16x8 kf = *(const bf16x8*)(Kc + off);
#pragma unroll
                for (int qt = 0; qt < 2; ++qt)
                    sa[qt][nt] = __builtin_amdgcn_mfma_f32_16x16x32_bf16(kf, qf[qt][ks], sa[qt][nt], 0, 0, 0);
            }
        }
        __builtin_amdgcn_s_setprio(0);

        // PV(t-1) operand preloads (from Pp / Vr; latency hides under SM)
        bf16x8 pf[2][2];
#pragma unroll
        for (int qt = 0; qt < 2; ++qt)
#pragma unroll
            for (int ks = 0; ks < 2; ++ks) {
                int poff = ((qt * 16 + lo16) * 128 + ks * 64 + g * 16) ^ rswz;
                pf[qt][ks] = *(const bf16x8*)(Pp + poff);
            }
        bf16x8 vf[2][4];
#pragma unroll
        for (int ks = 0; ks < 2; ++ks)
#pragma unroll
            for (int nd = 0; nd < 4; ++nd) {
                int row = nd * 16 + lo16;
                int off = (row * 128 + ks * 64 + g * 16) ^ ((row & 7) << 4);
                vf[ks][nd] = *(const bf16x8*)(Vr + off);
            }

        // SM(t): independent of PV(t-1) -> compiler interleaves VALU w/ MFMA
#pragma unroll
        for (int qt = 0; qt < 2; ++qt) {
            const int prow = qt * 16 + lo16;
#pragma unroll
            for (int nt = 0; nt < 4; ++nt) {
                float e0 = EXP2(sa[qt][nt][0]);
                float e1 = EXP2(sa[qt][nt][1]);
                float e2 = EXP2(sa[qt][nt][2]);
                float e3 = EXP2(sa[qt][nt][3]);
                ls4[qt] += (f32x4){e0, e1, e2, e3};
                bf16x4 p4 = {bfc(e0), bfc(e1), bfc(e2), bfc(e3)};
                int wb = (prow * 128 + nt * 32 + g * 8) ^ rswz;
                *(bf16x4*)(Pc + wb) = p4;
            }
        }

        // PV(t-1) MFMAs
        __builtin_amdgcn_s_setprio(1);
#pragma unroll
        for (int ks = 0; ks < 2; ++ks)
#pragma unroll
            for (int nd = 0; nd < 4; ++nd)
#pragma unroll
                for (int qt = 0; qt < 2; ++qt)
                    oa[qt][nd] = __builtin_amdgcn_mfma_f32_16x16x32_bf16(vf[ks][nd], pf[qt][ks], oa[qt][nd], 0, 0, 0);
        __builtin_amdgcn_s_setprio(0);

        pbp += 64;
        __syncthreads();
        { char* tk = Kc; Kc = Kw; Kw = tk;
          char* tv = Vr; Vr = Vn; Vn = Vw; Vw = tv;
          char* tp = Pc; Pc = Pp; Pp = tp; }
    }

    // ---------------- epilogue: PV(NT-1) (P in Pp, V in Vr after rotation) -
    {
#pragma unroll
        for (int ks = 0; ks < 2; ++ks) {
            bf16x8 pf[2];
#pragma unroll
            for (int qt = 0; qt < 2; ++qt) {
                int poff = ((qt * 16 + lo16) * 128 + ks * 64 + g * 16) ^ rswz;
                pf[qt] = *(const bf16x8*)(Pp + poff);
            }
#pragma unroll
            for (int nd = 0; nd < 4; ++nd) {
                int row = nd * 16 + lo16;
                int off = (row * 128 + ks * 64 + g * 16) ^ ((row & 7) << 4);
                bf16x8 vfl = *(const bf16x8*)(Vr + off);
#pragma unroll
                for (int qt = 0; qt < 2; ++qt)
                    oa[qt][nd] = __builtin_amdgcn_mfma_f32_16x16x32_bf16(vfl, pf[qt], oa[qt][nd], 0, 0, 0);
            }
        }
    }

    // ---- epilogue: reduce l across g, write ctx
#pragma unroll
    for (int qt = 0; qt < 2; ++qt) {
        float lt = (ls4[qt][0] + ls4[qt][1]) + (ls4[qt][2] + ls4[qt][3]);
        lt += __shfl_xor(lt, 16);
        lt += __shfl_xor(lt, 32);
        float linv = 1.0f / lt;
        const size_t crow =
            ((size_t)(bb * T_ + q0 + w * 32 + qt * 16 + lo16)) * NQ_ + hh * DM_;
#pragma unroll
        for (int nd = 0; nd < 4; ++nd) {
            bf16x4 u = {bfc(oa[qt][nd][0] * linv), bfc(oa[qt][nd][1] * linv),
                        bfc(oa[qt][nd][2] * linv), bfc(oa[qt][nd][3] * linv)};
            *(bf16x4*)&ctx[crow + nd * 16 + g * 4] = u;
        }
    }
}

// ---------------------------------------------------------------------------
extern "C" void kernel_launch(void* const* d_in, const int* in_sizes, int n_in,
                              void* d_out, int out_size, void* d_ws, size_t ws_size,
                              hipStream_t stream) {
    const float* data = (const float*)d_in[0];
    const float* mask = (const float*)d_in[1];
    const float* wq   = (const float*)d_in[2];
    const float* bq   = (const float*)d_in[3];
    const float* wk   = (const float*)d_in[4];
    const float* bk   = (const float*)d_in[5];
    const float* wv   = (const float*)d_in[6];
    const float* bv   = (const float*)d_in[7];
    const float* wo   = (const float*)d_in[8];
    const float* bo   = (const float*)d_in[9];
    float* out = (float*)d_out;

    char* ws = (char*)d_ws;
    const size_t MB = 1024 * 1024;
    unsigned short* Qh    = (unsigned short*)(ws);             // 8MB
    unsigned short* Kh    = (unsigned short*)(ws +  8 * MB);   // 8MB
    unsigned short* Vt    = (unsigned short*)(ws + 16 * MB);   // 8MB
    unsigned short* CTX   = (unsigned short*)(ws + 24 * MB);   // 8MB (bf16)
    unsigned short* dataB = (unsigned short*)(ws + 32 * MB);   // 4MB
    unsigned short* BtAll = (unsigned short*)(ws + 36 * MB);   // 3MB
    unsigned short* wot   = (unsigned short*)(ws + 39 * MB);   // 1MB
    float*          padb  = (float*)         (ws + 40 * MB);   // 16KB

    const int M = B_ * T_;                 // 4096
    const float alpha_q = 0.125f * 1.44269504089f;

    prep_kernel<<<4096, 256, 0, stream>>>(mask, padb, data, dataB,
                                          wq, wk, wv, BtAll, wo, wot);

    mgemm_qkv_kernel<<<dim3(3 * NQ_ / 128, M / 128), 256, 0, stream>>>(
        dataB, BtAll, bq, bk, bv, Qh, Kh, Vt, alpha_q);

    attn_kernel<<<512, 256, 0, stream>>>(Qh, Kh, Vt, padb, CTX);

    mgemm_out_kernel<<<dim3(D_ / 128, M / 64), 256, 0, stream>>>(
        CTX, wot, bo, out, M, D_, NQ_);
}

// Round 14
// 105.389 us; speedup vs baseline: 1.0820x; 1.0364x over previous
//
#include <hip/hip_runtime.h>
#include <hip/hip_bf16.h>

#define B_  2
#define T_  2048
#define D_  512
#define DM_ 64
#define H_  16
#define NQ_ (DM_*H_)   // 1024
#define NT_ (T_/64)    // 32 key tiles

typedef __bf16 bf16x8 __attribute__((ext_vector_type(8)));
typedef __bf16 bf16x4 __attribute__((ext_vector_type(4)));
typedef float  f32x4  __attribute__((ext_vector_type(4)));
typedef unsigned int u32;

static __device__ __forceinline__ __bf16 bfc(float x) { return (__bf16)x; }
static __device__ __forceinline__ unsigned short f2bf(float x) {
    __bf16 b = (__bf16)x;
    unsigned short u;
    __builtin_memcpy(&u, &b, 2);
    return u;
}

#if __has_builtin(__builtin_amdgcn_exp2f)
static __device__ __forceinline__ float EXP2(float x) { return __builtin_amdgcn_exp2f(x); }
#else
static __device__ __forceinline__ float EXP2(float x) {
    float r; asm("v_exp_f32 %0, %1\ns_nop 0" : "=v"(r) : "v"(x)); return r;
}
#endif

// async global->LDS, 16B per lane; dest = wave-uniform base + lane*16
#define GLOAD16(gp, lp) \
    __builtin_amdgcn_global_load_lds((const __attribute__((address_space(1))) u32*)(gp), \
                                     (__attribute__((address_space(3))) u32*)(lp), 16, 0, 0)

// ---------------------------------------------------------------------------
// fused prep: [0,1024) pad | [1024,2048) data cvt | [2048,3584) qkv wtrans |
// [3584,4096) wo wtrans
// ---------------------------------------------------------------------------
__global__ __launch_bounds__(256)
void prep_kernel(const float* __restrict__ mask, float* __restrict__ padb,
                 const float* __restrict__ data, unsigned short* __restrict__ dataB,
                 const float* __restrict__ wq, const float* __restrict__ wk,
                 const float* __restrict__ wv, unsigned short* __restrict__ btall,
                 const float* __restrict__ wo, unsigned short* __restrict__ wot)
{
    __shared__ float t[32][33];
    const int bid = blockIdx.x;
    const int tid = threadIdx.x;
    if (bid < 1024) {
        const int row  = bid * 4 + (tid >> 6);
        const int lane = tid & 63;
        const float* p = mask + (size_t)row * D_;
        float4 a = *(const float4*)&p[lane * 8];
        float4 b = *(const float4*)&p[lane * 8 + 4];
        float s = a.x + a.y + a.z + a.w + b.x + b.y + b.z + b.w;
#pragma unroll
        for (int off = 32; off; off >>= 1) s += __shfl_down(s, off);
        if (lane == 0) padb[row] = (s == 0.0f) ? -1e9f : 0.0f;
    } else if (bid < 2048) {
        int i = ((bid - 1024) * 256 + tid) * 8;
        float4 a = *(const float4*)&data[i];
        float4 b = *(const float4*)&data[i + 4];
        bf16x8 u = {bfc(a.x), bfc(a.y), bfc(a.z), bfc(a.w),
                    bfc(b.x), bfc(b.y), bfc(b.z), bfc(b.w)};
        *(bf16x8*)&dataB[i] = u;
    } else if (bid < 3584) {
        const int idx = bid - 2048;
        const int z = idx >> 9, rem = idx & 511;
        const int c0 = (rem & 31) * 32, r0 = (rem >> 5) * 32;   // C=1024, R=512
        const float* in = (z == 0) ? wq : (z == 1) ? wk : wv;
        unsigned short* out = btall + (size_t)z * NQ_ * D_;
        const int tx = tid & 31, ty = tid >> 5;
#pragma unroll
        for (int i = 0; i < 4; ++i)
            t[ty * 4 + i][tx] = in[(size_t)(r0 + ty * 4 + i) * NQ_ + c0 + tx];
        __syncthreads();
#pragma unroll
        for (int i = 0; i < 4; ++i)
            out[(size_t)(c0 + ty * 4 + i) * D_ + r0 + tx] = f2bf(t[tx][ty * 4 + i]);
    } else {
        const int idx = bid - 3584;
        const int c0 = (idx & 15) * 32, r0 = (idx >> 4) * 32;   // C=512, R=1024
        const int tx = tid & 31, ty = tid >> 5;
#pragma unroll
        for (int i = 0; i < 4; ++i)
            t[ty * 4 + i][tx] = wo[(size_t)(r0 + ty * 4 + i) * D_ + c0 + tx];
        __syncthreads();
#pragma unroll
        for (int i = 0; i < 4; ++i)
            wot[(size_t)(c0 + ty * 4 + i) * NQ_ + r0 + tx] = f2bf(t[tx][ty * 4 + i]);
    }
}

// ---------------------------------------------------------------------------
// fused QKV GEMM: A[4096,512] @ BtAll[3072,512]^T, gload_lds dbuf staging.
// seg 0 -> Qh head-major *alpha_q, 1 -> Kh head-major, 2 -> Vt transposed.
// ---------------------------------------------------------------------------
__global__ __launch_bounds__(256)
void mgemm_qkv_kernel(const unsigned short* __restrict__ A,
                      const unsigned short* __restrict__ BtAll,
                      const float* __restrict__ bq, const float* __restrict__ bk,
                      const float* __restrict__ bv,
                      unsigned short* __restrict__ Qh, unsigned short* __restrict__ Kh,
                      unsigned short* __restrict__ Vt, float alpha_q)
{
    const int K = D_;
    __shared__ __align__(16) unsigned short Al[2][128 * 64];
    __shared__ __align__(16) unsigned short Bl[2][128 * 64];

    const int tid = threadIdx.x;
    const int w  = tid >> 6, l = tid & 63;
    const int lo = l & 15,  g = l >> 4;
    const int wri = w >> 1, wci = w & 1;
    const int m0 = blockIdx.y * 128, n0 = blockIdx.x * 128;
    const int lrow = l >> 3;
    const int lslot = (l & 7) ^ lrow;     // pre-swizzled source slot

    f32x4 acc[4][4] = {};
    const int nk = K >> 6;   // 8

    // prologue: stage k-step 0 into buf0
#pragma unroll
    for (int p = 0; p < 4; ++p) {
        int br = w * 32 + p * 8;
        GLOAD16(A     + (size_t)(m0 + br + lrow) * K + lslot * 8, (char*)Al[0] + br * 128);
        GLOAD16(BtAll + (size_t)(n0 + br + lrow) * K + lslot * 8, (char*)Bl[0] + br * 128);
    }
    __syncthreads();

    for (int t = 0; t < nk; ++t) {
        const int cur = t & 1;
        if (t + 1 < nk) {
            const int k0 = (t + 1) << 6;
#pragma unroll
            for (int p = 0; p < 4; ++p) {
                int br = w * 32 + p * 8;
                GLOAD16(A     + (size_t)(m0 + br + lrow) * K + k0 + lslot * 8,
                        (char*)Al[cur ^ 1] + br * 128);
                GLOAD16(BtAll + (size_t)(n0 + br + lrow) * K + k0 + lslot * 8,
                        (char*)Bl[cur ^ 1] + br * 128);
            }
        }
#pragma unroll
        for (int kk = 0; kk < 2; ++kk) {
            bf16x8 af[4], bfr[4];
#pragma unroll
            for (int i = 0; i < 4; ++i) {
                int row = wri * 64 + i * 16 + lo;
                af[i] = *(const bf16x8*)&Al[cur][row * 64 + ((((kk << 2) + g) ^ (row & 7)) << 3)];
                int col = wci * 64 + i * 16 + lo;
                bfr[i] = *(const bf16x8*)&Bl[cur][col * 64 + ((((kk << 2) + g) ^ (col & 7)) << 3)];
            }
#pragma unroll
            for (int i = 0; i < 4; ++i)
#pragma unroll
                for (int j = 0; j < 4; ++j)
                    acc[i][j] = __builtin_amdgcn_mfma_f32_16x16x32_bf16(af[i], bfr[j], acc[i][j], 0, 0, 0);
        }
        __syncthreads();
    }

    const int seg = n0 >> 10;                  // 0:Q 1:K 2:V
    const int n0l = n0 & 1023;
    const float* bias = (seg == 0) ? bq : (seg == 1) ? bk : bv;
    const float alpha = (seg == 0) ? alpha_q : 1.0f;
    unsigned short* o16 = (seg == 0) ? Qh : (seg == 1) ? Kh : Vt;

    const int mb = m0 + wri * 64 + g * 4;
    float bb[4];
#pragma unroll
    for (int j = 0; j < 4; ++j) bb[j] = bias[n0l + wci * 64 + j * 16 + lo];
    const int head = lo;
    const int dmb  = (n0l >> 4) + wci * 4;
    if (seg < 2) {
#pragma unroll
        for (int i = 0; i < 4; ++i)
#pragma unroll
            for (int jj = 0; jj < 4; ++jj) {
                int m = mb + i * 16 + jj;
                int t = m & (T_ - 1), bidx = m >> 11;
                bf16x4 u = {bfc((acc[i][0][jj] + bb[0]) * alpha),
                            bfc((acc[i][1][jj] + bb[1]) * alpha),
                            bfc((acc[i][2][jj] + bb[2]) * alpha),
                            bfc((acc[i][3][jj] + bb[3]) * alpha)};
                *(bf16x4*)&o16[(((size_t)(bidx * H_ + head)) * T_ + t) * DM_ + dmb] = u;
            }
    } else {
#pragma unroll
        for (int i = 0; i < 4; ++i)
#pragma unroll
            for (int j = 0; j < 4; ++j) {
                int m = mb + i * 16;
                int t = m & (T_ - 1), bidx = m >> 11;
                bf16x4 u = {bfc(acc[i][j][0] + bb[j]), bfc(acc[i][j][1] + bb[j]),
                            bfc(acc[i][j][2] + bb[j]), bfc(acc[i][j][3] + bb[j])};
                *(bf16x4*)&o16[((size_t)(bidx * H_ + head) * DM_ + dmb + j) * T_ + t] = u;
            }
    }
}

// ---------------------------------------------------------------------------
// out-projection GEMM (fp32 out), 64x128 tile, gload_lds dbuf staging.
// ---------------------------------------------------------------------------
__global__ __launch_bounds__(256)
void mgemm_out_kernel(const unsigned short* __restrict__ A,
                      const unsigned short* __restrict__ Bt,
                      const float* __restrict__ bias, float* __restrict__ out,
                      int M, int N, int K)
{
    __shared__ __align__(16) unsigned short Al[2][64 * 64];
    __shared__ __align__(16) unsigned short Bl[2][128 * 64];

    const int tid = threadIdx.x;
    const int w  = tid >> 6, l = tid & 63;
    const int lo = l & 15,  g = l >> 4;
    const int wri = w >> 1, wci = w & 1;
    const int m0 = blockIdx.y * 64, n0 = blockIdx.x * 128;
    const int lrow = l >> 3;
    const int lslot = (l & 7) ^ lrow;

    f32x4 acc[2][4] = {};
    const int nk = K >> 6;

#pragma unroll
    for (int p = 0; p < 2; ++p) {
        int br = w * 16 + p * 8;
        GLOAD16(A + (size_t)(m0 + br + lrow) * K + lslot * 8, (char*)Al[0] + br * 128);
    }
#pragma unroll
    for (int p = 0; p < 4; ++p) {
        int br = w * 32 + p * 8;
        GLOAD16(Bt + (size_t)(n0 + br + lrow) * K + lslot * 8, (char*)Bl[0] + br * 128);
    }
    __syncthreads();

    for (int t = 0; t < nk; ++t) {
        const int cur = t & 1;
        if (t + 1 < nk) {
            const int k0 = (t + 1) << 6;
#pragma unroll
            for (int p = 0; p < 2; ++p) {
                int br = w * 16 + p * 8;
                GLOAD16(A + (size_t)(m0 + br + lrow) * K + k0 + lslot * 8,
                        (char*)Al[cur ^ 1] + br * 128);
            }
#pragma unroll
            for (int p = 0; p < 4; ++p) {
                int br = w * 32 + p * 8;
                GLOAD16(Bt + (size_t)(n0 + br + lrow) * K + k0 + lslot * 8,
                        (char*)Bl[cur ^ 1] + br * 128);
            }
        }
#pragma unroll
        for (int kk = 0; kk < 2; ++kk) {
            bf16x8 af[2], bfr[4];
#pragma unroll
            for (int i = 0; i < 2; ++i) {
                int row = wri * 32 + i * 16 + lo;
                af[i] = *(const bf16x8*)&Al[cur][row * 64 + ((((kk << 2) + g) ^ (row & 7)) << 3)];
            }
#pragma unroll
            for (int j = 0; j < 4; ++j) {
                int col = wci * 64 + j * 16 + lo;
                bfr[j] = *(const bf16x8*)&Bl[cur][col * 64 + ((((kk << 2) + g) ^ (col & 7)) << 3)];
            }
#pragma unroll
            for (int i = 0; i < 2; ++i)
#pragma unroll
                for (int j = 0; j < 4; ++j)
                    acc[i][j] = __builtin_amdgcn_mfma_f32_16x16x32_bf16(af[i], bfr[j], acc[i][j], 0, 0, 0);
        }
        __syncthreads();
    }

    const int mb = m0 + wri * 32 + g * 4;
#pragma unroll
    for (int j = 0; j < 4; ++j) {
        int n = n0 + wci * 64 + j * 16 + lo;
        float bb = bias[n];
#pragma unroll
        for (int i = 0; i < 2; ++i)
#pragma unroll
            for (int jj = 0; jj < 4; ++jj) {
                int m = mb + i * 16 + jj;
                out[(size_t)m * N + n] = acc[i][j][jj] + bb;
            }
    }
}

// ---------------------------------------------------------------------------
// MFMA flash attention v14 = R13 with the overlap UNPINNED:
//  - no setprio around PV (ordered intrinsics were serializing SM and PV);
//  - SM(t) and PV(t-1) manually interleaved at quad granularity (TRANS/VALU
//    and MFMA pipes co-issue; pf/vf preloaded into regs before the region);
//  - pad-bias register-pipelined (pbn loaded for t+1, consumed next iter;
//    no pbs LDS array, no in-iter vmcnt wait on pb).
// 4 waves x 32 q, QBLK=128, K dbuf, V tri-buf, P LDS dbuf, XCD-aware grid.
// ---------------------------------------------------------------------------
__global__ __launch_bounds__(256, 2)
void attn_kernel(const unsigned short* __restrict__ Qh,
                 const unsigned short* __restrict__ Kh,
                 const unsigned short* __restrict__ Vt,
                 const float* __restrict__ padb,
                 unsigned short* __restrict__ ctx)
{
    __shared__ __align__(16) unsigned short Ks[2][64 * 64];      // 16KB
    __shared__ __align__(16) unsigned short Vs[3][64 * 64];      // 24KB
    __shared__ __align__(16) unsigned short Ps[4][2][32 * 64];   // 32KB

    const int tid  = threadIdx.x;
    const int w    = tid >> 6;        // 0..3
    const int l    = tid & 63;
    const int lo16 = l & 15;
    const int g    = l >> 4;
    const int lrow = l >> 3;          // 0..7
    const int lslot = (l & 7) ^ lrow; // pre-swizzled source slot

    // XCD-aware decode: blocks of one head cluster on one XCD's L2.
    const int f   = blockIdx.x;
    const int s   = f >> 3;
    const int bh  = (f & 7) * 4 + (s >> 4);
    const int q0  = (s & 15) * 128;
    const int bb  = bh >> 4;
    const int hh  = bh & 15;

    bf16x8 qf[2][2];
#pragma unroll
    for (int qt = 0; qt < 2; ++qt) {
        const unsigned short* Qp =
            Qh + ((size_t)bh * T_ + q0 + w * 32 + qt * 16 + lo16) * DM_ + g * 8;
        qf[qt][0] = *(const bf16x8*)(Qp);
        qf[qt][1] = *(const bf16x8*)(Qp + 32);
    }

    const unsigned short* kgp =
        Kh + (size_t)bh * T_ * DM_ + (size_t)(w * 16 + lrow) * DM_ + lslot * 8;
    const unsigned short* vgp =
        Vt + (size_t)bh * DM_ * T_ + (size_t)(w * 16 + lrow) * T_ + lslot * 8;
    const float* pbase = padb + bb * T_ + g * 4;

    // pad bias for tile 0 -> regs
    f32x4 pbc[4];
#pragma unroll
    for (int nt = 0; nt < 4; ++nt) pbc[nt] = *(const f32x4*)(pbase + nt * 16);

    // stage tile 0 -> Ks[0], Vs[0]
    GLOAD16(kgp,           (char*)Ks[0] + (w * 16) * 128);
    GLOAD16(kgp + 8 * DM_, (char*)Ks[0] + (w * 16 + 8) * 128);
    GLOAD16(vgp,           (char*)Vs[0] + (w * 16) * 128);
    GLOAD16(vgp + 8 * T_,  (char*)Vs[0] + (w * 16 + 8) * 128);
    kgp += 64 * DM_;
    vgp += 64;

    const int rswz = (lo16 & 7) << 4;
    __syncthreads();

    f32x4 oa[2][4] = {};
    f32x4 ls4[2] = {};

    char* Kc = (char*)Ks[0];          // K(t) read
    char* Kw = (char*)Ks[1];          // K(t+1) staging target
    char* Vr = (char*)Vs[2];          // V(t-1) read (unused at t=0)
    char* Vn = (char*)Vs[0];          // V(t)   (idle this iter)
    char* Vw = (char*)Vs[1];          // V(t+1) staging target
    char* Pc = (char*)&Ps[w][0][0];   // P(t) write
    char* Pp = (char*)&Ps[w][1][0];   // P(t-1) read

    // ---------------- peeled iteration 0: pb(1); stage(1); QK(0); SM(0) ----
    {
        f32x4 pbn[4];
#pragma unroll
        for (int nt = 0; nt < 4; ++nt)
            pbn[nt] = *(const f32x4*)(pbase + 64 + nt * 16);
        GLOAD16(kgp,           Kw + (w * 16) * 128);
        GLOAD16(kgp + 8 * DM_, Kw + (w * 16 + 8) * 128);
        GLOAD16(vgp,           Vw + (w * 16) * 128);
        GLOAD16(vgp + 8 * T_,  Vw + (w * 16 + 8) * 128);
        kgp += 64 * DM_;
        vgp += 64;

        f32x4 sa[2][4];
#pragma unroll
        for (int nt = 0; nt < 4; ++nt) {
            sa[0][nt] = pbc[nt];
            sa[1][nt] = pbc[nt];
        }
        __builtin_amdgcn_s_setprio(1);
#pragma unroll
        for (int ks = 0; ks < 2; ++ks) {
#pragma unroll
            for (int nt = 0; nt < 4; ++nt) {
                int row = nt * 16 + lo16;
                int off = (row * 128 + ks * 64 + g * 16) ^ ((row & 7) << 4);
                bf16x8 kf = *(const bf16x8*)(Kc + off);
#pragma unroll
                for (int qt = 0; qt < 2; ++qt)
                    sa[qt][nt] = __builtin_amdgcn_mfma_f32_16x16x32_bf16(kf, qf[qt][ks], sa[qt][nt], 0, 0, 0);
            }
        }
        __builtin_amdgcn_s_setprio(0);
#pragma unroll
        for (int qt = 0; qt < 2; ++qt) {
            const int prow = qt * 16 + lo16;
#pragma unroll
            for (int nt = 0; nt < 4; ++nt) {
                float e0 = EXP2(sa[qt][nt][0]);
                float e1 = EXP2(sa[qt][nt][1]);
                float e2 = EXP2(sa[qt][nt][2]);
                float e3 = EXP2(sa[qt][nt][3]);
                ls4[qt] += (f32x4){e0, e1, e2, e3};
                bf16x4 p4 = {bfc(e0), bfc(e1), bfc(e2), bfc(e3)};
                int wb = (prow * 128 + nt * 32 + g * 8) ^ rswz;
                *(bf16x4*)(Pc + wb) = p4;
            }
        }
#pragma unroll
        for (int nt = 0; nt < 4; ++nt) pbc[nt] = pbn[nt];
        __syncthreads();
        { char* tk = Kc; Kc = Kw; Kw = tk;
          char* tv = Vr; Vr = Vn; Vn = Vw; Vw = tv;
          char* tp = Pc; Pc = Pp; Pp = tp; }
    }

    // ---------------- main loop: t = 1 .. NT-1 -----------------------------
    for (int it = 1; it < NT_; ++it) {
        // pb(t+1) first (consumed next iter; barrier drains anyway)
        f32x4 pbn[4];
        if (it + 1 < NT_) {
#pragma unroll
            for (int nt = 0; nt < 4; ++nt)
                pbn[nt] = *(const f32x4*)(pbase + (it + 1) * 64 + nt * 16);
            GLOAD16(kgp,           Kw + (w * 16) * 128);
            GLOAD16(kgp + 8 * DM_, Kw + (w * 16 + 8) * 128);
            GLOAD16(vgp,           Vw + (w * 16) * 128);
            GLOAD16(vgp + 8 * T_,  Vw + (w * 16 + 8) * 128);
            kgp += 64 * DM_;
            vgp += 64;
        }

        // QK(t): C-init = pad bias (registers, loaded last iter)
        f32x4 sa[2][4];
#pragma unroll
        for (int nt = 0; nt < 4; ++nt) {
            sa[0][nt] = pbc[nt];
            sa[1][nt] = pbc[nt];
        }
        __builtin_amdgcn_s_setprio(1);
#pragma unroll
        for (int ks = 0; ks < 2; ++ks) {
#pragma unroll
            for (int nt = 0; nt < 4; ++nt) {
                int row = nt * 16 + lo16;
                int off = (row * 128 + ks * 64 + g * 16) ^ ((row & 7) << 4);
                bf16x8 kf = *(const bf16x8*)(Kc + off);
#pragma unroll
                for (int qt = 0; qt < 2; ++qt)
                    sa[qt][nt] = __builtin_amdgcn_mfma_f32_16x16x32_bf16(kf, qf[qt][ks], sa[qt][nt], 0, 0, 0);
            }
        }
        __builtin_amdgcn_s_setprio(0);

        // PV(t-1) operand preloads (Pp / Vr)
        bf16x8 pf[2][2];
#pragma unroll
        for (int qt = 0; qt < 2; ++qt)
#pragma unroll
            for (int ks = 0; ks < 2; ++ks) {
                int poff = ((qt * 16 + lo16) * 128 + ks * 64 + g * 16) ^ rswz;
                pf[qt][ks] = *(const bf16x8*)(Pp + poff);
            }
        bf16x8 vf[2][4];
#pragma unroll
        for (int ks = 0; ks < 2; ++ks)
#pragma unroll
            for (int nd = 0; nd < 4; ++nd) {
                int row = nd * 16 + lo16;
                int off = (row * 128 + ks * 64 + g * 16) ^ ((row & 7) << 4);
                vf[ks][nd] = *(const bf16x8*)(Vr + off);
            }

        // SM(t) interleaved with PV(t-1): 8 chunks, each = one exp-quad-pair
        // plus 2 PV MFMAs; no ordered intrinsics inside -> pipes co-issue.
#pragma unroll
        for (int c = 0; c < 8; ++c) {
            const int qt = c >> 2, nt = c & 3;
            float e0 = EXP2(sa[qt][nt][0]);
            float e1 = EXP2(sa[qt][nt][1]);
            float e2 = EXP2(sa[qt][nt][2]);
            float e3 = EXP2(sa[qt][nt][3]);
            ls4[qt] += (f32x4){e0, e1, e2, e3};
            bf16x4 p4 = {bfc(e0), bfc(e1), bfc(e2), bfc(e3)};
            int wb = ((qt * 16 + lo16) * 128 + nt * 32 + g * 8) ^ rswz;
            *(bf16x4*)(Pc + wb) = p4;
            // 2 PV MFMAs: chunk c -> (ks = c>>2, nd = c&3), qt = 0 and 1
            const int ks = c >> 2, nd = c & 3;
            oa[0][nd] = __builtin_amdgcn_mfma_f32_16x16x32_bf16(vf[ks][nd], pf[0][ks], oa[0][nd], 0, 0, 0);
            oa[1][nd] = __builtin_amdgcn_mfma_f32_16x16x32_bf16(vf[ks][nd], pf[1][ks], oa[1][nd], 0, 0, 0);
        }

        if (it + 1 < NT_) {
#pragma unroll
            for (int nt = 0; nt < 4; ++nt) pbc[nt] = pbn[nt];
        }
        __syncthreads();
        { char* tk = Kc; Kc = Kw; Kw = tk;
          char* tv = Vr; Vr = Vn; Vn = Vw; Vw = tv;
          char* tp = Pc; Pc = Pp; Pp = tp; }
    }

    // ---------------- epilogue: PV(NT-1) (P in Pp, V in Vr after rotation) -
    {
#pragma unroll
        for (int ks = 0; ks < 2; ++ks) {
            bf16x8 pf[2];
#pragma unroll
            for (int qt = 0; qt < 2; ++qt) {
                int poff = ((qt * 16 + lo16) * 128 + ks * 64 + g * 16) ^ rswz;
                pf[qt] = *(const bf16x8*)(Pp + poff);
            }
#pragma unroll
            for (int nd = 0; nd < 4; ++nd) {
                int row = nd * 16 + lo16;
                int off = (row * 128 + ks * 64 + g * 16) ^ ((row & 7) << 4);
                bf16x8 vfl = *(const bf16x8*)(Vr + off);
#pragma unroll
                for (int qt = 0; qt < 2; ++qt)
                    oa[qt][nd] = __builtin_amdgcn_mfma_f32_16x16x32_bf16(vfl, pf[qt], oa[qt][nd], 0, 0, 0);
            }
        }
    }

    // ---- epilogue: reduce l across g, write ctx
#pragma unroll
    for (int qt = 0; qt < 2; ++qt) {
        float lt = (ls4[qt][0] + ls4[qt][1]) + (ls4[qt][2] + ls4[qt][3]);
        lt += __shfl_xor(lt, 16);
        lt += __shfl_xor(lt, 32);
        float linv = 1.0f / lt;
        const size_t crow =
            ((size_t)(bb * T_ + q0 + w * 32 + qt * 16 + lo16)) * NQ_ + hh * DM_;
#pragma unroll
        for (int nd = 0; nd < 4; ++nd) {
            bf16x4 u = {bfc(oa[qt][nd][0] * linv), bfc(oa[qt][nd][1] * linv),
                        bfc(oa[qt][nd][2] * linv), bfc(oa[qt][nd][3] * linv)};
            *(bf16x4*)&ctx[crow + nd * 16 + g * 4] = u;
        }
    }
}

// ---------------------------------------------------------------------------
extern "C" void kernel_launch(void* const* d_in, const int* in_sizes, int n_in,
                              void* d_out, int out_size, void* d_ws, size_t ws_size,
                              hipStream_t stream) {
    const float* data = (const float*)d_in[0];
    const float* mask = (const float*)d_in[1];
    const float* wq   = (const float*)d_in[2];
    const float* bq   = (const float*)d_in[3];
    const float* wk   = (const float*)d_in[4];
    const float* bk   = (const float*)d_in[5];
    const float* wv   = (const float*)d_in[6];
    const float* bv   = (const float*)d_in[7];
    const float* wo   = (const float*)d_in[8];
    const float* bo   = (const float*)d_in[9];
    float* out = (float*)d_out;

    char* ws = (char*)d_ws;
    const size_t MB = 1024 * 1024;
    unsigned short* Qh    = (unsigned short*)(ws);             // 8MB
    unsigned short* Kh    = (unsigned short*)(ws +  8 * MB);   // 8MB
    unsigned short* Vt    = (unsigned short*)(ws + 16 * MB);   // 8MB
    unsigned short* CTX   = (unsigned short*)(ws + 24 * MB);   // 8MB (bf16)
    unsigned short* dataB = (unsigned short*)(ws + 32 * MB);   // 4MB
    unsigned short* BtAll = (unsigned short*)(ws + 36 * MB);   // 3MB
    unsigned short* wot   = (unsigned short*)(ws + 39 * MB);   // 1MB
    float*          padb  = (float*)         (ws + 40 * MB);   // 16KB

    const int M = B_ * T_;                 // 4096
    const float alpha_q = 0.125f * 1.44269504089f;

    prep_kernel<<<4096, 256, 0, stream>>>(mask, padb, data, dataB,
                                          wq, wk, wv, BtAll, wo, wot);

    mgemm_qkv_kernel<<<dim3(3 * NQ_ / 128, M / 128), 256, 0, stream>>>(
        dataB, BtAll, bq, bk, bv, Qh, Kh, Vt, alpha_q);

    attn_kernel<<<512, 256, 0, stream>>>(Qh, Kh, Vt, padb, CTX);

    mgemm_out_kernel<<<dim3(D_ / 128, M / 64), 256, 0, stream>>>(
        CTX, wot, bo, out, M, D_, NQ_);
}

// Round 15
// 105.274 us; speedup vs baseline: 1.0832x; 1.0011x over previous
//
#include <hip/hip_runtime.h>
#include <hip/hip_bf16.h>

#define B_  2
#define T_  2048
#define D_  512
#define DM_ 64
#define H_  16
#define NQ_ (DM_*H_)   // 1024
#define NP_ (T_/128)   // 16 phases (2 key-tiles each)

typedef __bf16 bf16x8 __attribute__((ext_vector_type(8)));
typedef __bf16 bf16x4 __attribute__((ext_vector_type(4)));
typedef float  f32x4  __attribute__((ext_vector_type(4)));
typedef unsigned int u32;

static __device__ __forceinline__ __bf16 bfc(float x) { return (__bf16)x; }
static __device__ __forceinline__ unsigned short f2bf(float x) {
    __bf16 b = (__bf16)x;
    unsigned short u;
    __builtin_memcpy(&u, &b, 2);
    return u;
}
static __device__ __forceinline__ u32 pack2bf(float a, float b) {
    return (u32)f2bf(a) | ((u32)f2bf(b) << 16);
}

#if __has_builtin(__builtin_amdgcn_exp2f)
static __device__ __forceinline__ float EXP2(float x) { return __builtin_amdgcn_exp2f(x); }
#else
static __device__ __forceinline__ float EXP2(float x) {
    float r; asm("v_exp_f32 %0, %1\ns_nop 0" : "=v"(r) : "v"(x)); return r;
}
#endif

// async global->LDS, 16B per lane; dest = wave-uniform base + lane*16
#define GLOAD16(gp, lp) \
    __builtin_amdgcn_global_load_lds((const __attribute__((address_space(1))) u32*)(gp), \
                                     (__attribute__((address_space(3))) u32*)(lp), 16, 0, 0)

// ---------------------------------------------------------------------------
// fused prep: [0,1024) pad | [1024,2048) data cvt | [2048,3584) qkv wtrans |
// [3584,4096) wo wtrans
// ---------------------------------------------------------------------------
__global__ __launch_bounds__(256)
void prep_kernel(const float* __restrict__ mask, float* __restrict__ padb,
                 const float* __restrict__ data, unsigned short* __restrict__ dataB,
                 const float* __restrict__ wq, const float* __restrict__ wk,
                 const float* __restrict__ wv, unsigned short* __restrict__ btall,
                 const float* __restrict__ wo, unsigned short* __restrict__ wot)
{
    __shared__ float t[32][33];
    const int bid = blockIdx.x;
    const int tid = threadIdx.x;
    if (bid < 1024) {
        const int row  = bid * 4 + (tid >> 6);
        const int lane = tid & 63;
        const float* p = mask + (size_t)row * D_;
        float4 a = *(const float4*)&p[lane * 8];
        float4 b = *(const float4*)&p[lane * 8 + 4];
        float s = a.x + a.y + a.z + a.w + b.x + b.y + b.z + b.w;
#pragma unroll
        for (int off = 32; off; off >>= 1) s += __shfl_down(s, off);
        if (lane == 0) padb[row] = (s == 0.0f) ? -1e9f : 0.0f;
    } else if (bid < 2048) {
        int i = ((bid - 1024) * 256 + tid) * 8;
        float4 a = *(const float4*)&data[i];
        float4 b = *(const float4*)&data[i + 4];
        bf16x8 u = {bfc(a.x), bfc(a.y), bfc(a.z), bfc(a.w),
                    bfc(b.x), bfc(b.y), bfc(b.z), bfc(b.w)};
        *(bf16x8*)&dataB[i] = u;
    } else if (bid < 3584) {
        const int idx = bid - 2048;
        const int z = idx >> 9, rem = idx & 511;
        const int c0 = (rem & 31) * 32, r0 = (rem >> 5) * 32;   // C=1024, R=512
        const float* in = (z == 0) ? wq : (z == 1) ? wk : wv;
        unsigned short* out = btall + (size_t)z * NQ_ * D_;
        const int tx = tid & 31, ty = tid >> 5;
#pragma unroll
        for (int i = 0; i < 4; ++i)
            t[ty * 4 + i][tx] = in[(size_t)(r0 + ty * 4 + i) * NQ_ + c0 + tx];
        __syncthreads();
#pragma unroll
        for (int i = 0; i < 4; ++i)
            out[(size_t)(c0 + ty * 4 + i) * D_ + r0 + tx] = f2bf(t[tx][ty * 4 + i]);
    } else {
        const int idx = bid - 3584;
        const int c0 = (idx & 15) * 32, r0 = (idx >> 4) * 32;   // C=512, R=1024
        const int tx = tid & 31, ty = tid >> 5;
#pragma unroll
        for (int i = 0; i < 4; ++i)
            t[ty * 4 + i][tx] = wo[(size_t)(r0 + ty * 4 + i) * D_ + c0 + tx];
        __syncthreads();
#pragma unroll
        for (int i = 0; i < 4; ++i)
            wot[(size_t)(c0 + ty * 4 + i) * NQ_ + r0 + tx] = f2bf(t[tx][ty * 4 + i]);
    }
}

// ---------------------------------------------------------------------------
// fused QKV GEMM: A[4096,512] @ BtAll[3072,512]^T, gload_lds dbuf staging.
// seg 0 -> Qh head-major *alpha_q, 1 -> Kh head-major, 2 -> Vt transposed.
// ---------------------------------------------------------------------------
__global__ __launch_bounds__(256)
void mgemm_qkv_kernel(const unsigned short* __restrict__ A,
                      const unsigned short* __restrict__ BtAll,
                      const float* __restrict__ bq, const float* __restrict__ bk,
                      const float* __restrict__ bv,
                      unsigned short* __restrict__ Qh, unsigned short* __restrict__ Kh,
                      unsigned short* __restrict__ Vt, float alpha_q)
{
    const int K = D_;
    __shared__ __align__(16) unsigned short Al[2][128 * 64];
    __shared__ __align__(16) unsigned short Bl[2][128 * 64];

    const int tid = threadIdx.x;
    const int w  = tid >> 6, l = tid & 63;
    const int lo = l & 15,  g = l >> 4;
    const int wri = w >> 1, wci = w & 1;
    const int m0 = blockIdx.y * 128, n0 = blockIdx.x * 128;
    const int lrow = l >> 3;
    const int lslot = (l & 7) ^ lrow;     // pre-swizzled source slot

    f32x4 acc[4][4] = {};
    const int nk = K >> 6;   // 8

    // prologue: stage k-step 0 into buf0
#pragma unroll
    for (int p = 0; p < 4; ++p) {
        int br = w * 32 + p * 8;
        GLOAD16(A     + (size_t)(m0 + br + lrow) * K + lslot * 8, (char*)Al[0] + br * 128);
        GLOAD16(BtAll + (size_t)(n0 + br + lrow) * K + lslot * 8, (char*)Bl[0] + br * 128);
    }
    __syncthreads();

    for (int t = 0; t < nk; ++t) {
        const int cur = t & 1;
        if (t + 1 < nk) {
            const int k0 = (t + 1) << 6;
#pragma unroll
            for (int p = 0; p < 4; ++p) {
                int br = w * 32 + p * 8;
                GLOAD16(A     + (size_t)(m0 + br + lrow) * K + k0 + lslot * 8,
                        (char*)Al[cur ^ 1] + br * 128);
                GLOAD16(BtAll + (size_t)(n0 + br + lrow) * K + k0 + lslot * 8,
                        (char*)Bl[cur ^ 1] + br * 128);
            }
        }
#pragma unroll
        for (int kk = 0; kk < 2; ++kk) {
            bf16x8 af[4], bfr[4];
#pragma unroll
            for (int i = 0; i < 4; ++i) {
                int row = wri * 64 + i * 16 + lo;
                af[i] = *(const bf16x8*)&Al[cur][row * 64 + ((((kk << 2) + g) ^ (row & 7)) << 3)];
                int col = wci * 64 + i * 16 + lo;
                bfr[i] = *(const bf16x8*)&Bl[cur][col * 64 + ((((kk << 2) + g) ^ (col & 7)) << 3)];
            }
#pragma unroll
            for (int i = 0; i < 4; ++i)
#pragma unroll
                for (int j = 0; j < 4; ++j)
                    acc[i][j] = __builtin_amdgcn_mfma_f32_16x16x32_bf16(af[i], bfr[j], acc[i][j], 0, 0, 0);
        }
        __syncthreads();
    }

    const int seg = n0 >> 10;                  // 0:Q 1:K 2:V
    const int n0l = n0 & 1023;
    const float* bias = (seg == 0) ? bq : (seg == 1) ? bk : bv;
    const float alpha = (seg == 0) ? alpha_q : 1.0f;
    unsigned short* o16 = (seg == 0) ? Qh : (seg == 1) ? Kh : Vt;

    const int mb = m0 + wri * 64 + g * 4;
    float bb[4];
#pragma unroll
    for (int j = 0; j < 4; ++j) bb[j] = bias[n0l + wci * 64 + j * 16 + lo];
    const int head = lo;
    const int dmb  = (n0l >> 4) + wci * 4;
    if (seg < 2) {
#pragma unroll
        for (int i = 0; i < 4; ++i)
#pragma unroll
            for (int jj = 0; jj < 4; ++jj) {
                int m = mb + i * 16 + jj;
                int t = m & (T_ - 1), bidx = m >> 11;
                bf16x4 u = {bfc((acc[i][0][jj] + bb[0]) * alpha),
                            bfc((acc[i][1][jj] + bb[1]) * alpha),
                            bfc((acc[i][2][jj] + bb[2]) * alpha),
                            bfc((acc[i][3][jj] + bb[3]) * alpha)};
                *(bf16x4*)&o16[(((size_t)(bidx * H_ + head)) * T_ + t) * DM_ + dmb] = u;
            }
    } else {
#pragma unroll
        for (int i = 0; i < 4; ++i)
#pragma unroll
            for (int j = 0; j < 4; ++j) {
                int m = mb + i * 16;
                int t = m & (T_ - 1), bidx = m >> 11;
                bf16x4 u = {bfc(acc[i][j][0] + bb[j]), bfc(acc[i][j][1] + bb[j]),
                            bfc(acc[i][j][2] + bb[j]), bfc(acc[i][j][3] + bb[j])};
                *(bf16x4*)&o16[((size_t)(bidx * H_ + head) * DM_ + dmb + j) * T_ + t] = u;
            }
    }
}

// ---------------------------------------------------------------------------
// out-projection GEMM (fp32 out), 64x128 tile, gload_lds dbuf staging.
// ---------------------------------------------------------------------------
__global__ __launch_bounds__(256)
void mgemm_out_kernel(const unsigned short* __restrict__ A,
                      const unsigned short* __restrict__ Bt,
                      const float* __restrict__ bias, float* __restrict__ out,
                      int M, int N, int K)
{
    __shared__ __align__(16) unsigned short Al[2][64 * 64];
    __shared__ __align__(16) unsigned short Bl[2][128 * 64];

    const int tid = threadIdx.x;
    const int w  = tid >> 6, l = tid & 63;
    const int lo = l & 15,  g = l >> 4;
    const int wri = w >> 1, wci = w & 1;
    const int m0 = blockIdx.y * 64, n0 = blockIdx.x * 128;
    const int lrow = l >> 3;
    const int lslot = (l & 7) ^ lrow;

    f32x4 acc[2][4] = {};
    const int nk = K >> 6;

#pragma unroll
    for (int p = 0; p < 2; ++p) {
        int br = w * 16 + p * 8;
        GLOAD16(A + (size_t)(m0 + br + lrow) * K + lslot * 8, (char*)Al[0] + br * 128);
    }
#pragma unroll
    for (int p = 0; p < 4; ++p) {
        int br = w * 32 + p * 8;
        GLOAD16(Bt + (size_t)(n0 + br + lrow) * K + lslot * 8, (char*)Bl[0] + br * 128);
    }
    __syncthreads();

    for (int t = 0; t < nk; ++t) {
        const int cur = t & 1;
        if (t + 1 < nk) {
            const int k0 = (t + 1) << 6;
#pragma unroll
            for (int p = 0; p < 2; ++p) {
                int br = w * 16 + p * 8;
                GLOAD16(A + (size_t)(m0 + br + lrow) * K + k0 + lslot * 8,
                        (char*)Al[cur ^ 1] + br * 128);
            }
#pragma unroll
            for (int p = 0; p < 4; ++p) {
                int br = w * 32 + p * 8;
                GLOAD16(Bt + (size_t)(n0 + br + lrow) * K + k0 + lslot * 8,
                        (char*)Bl[cur ^ 1] + br * 128);
            }
        }
#pragma unroll
        for (int kk = 0; kk < 2; ++kk) {
            bf16x8 af[2], bfr[4];
#pragma unroll
            for (int i = 0; i < 2; ++i) {
                int row = wri * 32 + i * 16 + lo;
                af[i] = *(const bf16x8*)&Al[cur][row * 64 + ((((kk << 2) + g) ^ (row & 7)) << 3)];
            }
#pragma unroll
            for (int j = 0; j < 4; ++j) {
                int col = wci * 64 + j * 16 + lo;
                bfr[j] = *(const bf16x8*)&Bl[cur][col * 64 + ((((kk << 2) + g) ^ (col & 7)) << 3)];
            }
#pragma unroll
            for (int i = 0; i < 2; ++i)
#pragma unroll
                for (int j = 0; j < 4; ++j)
                    acc[i][j] = __builtin_amdgcn_mfma_f32_16x16x32_bf16(af[i], bfr[j], acc[i][j], 0, 0, 0);
        }
        __syncthreads();
    }

    const int mb = m0 + wri * 32 + g * 4;
#pragma unroll
    for (int j = 0; j < 4; ++j) {
        int n = n0 + wci * 64 + j * 16 + lo;
        float bb = bias[n];
#pragma unroll
        for (int i = 0; i < 2; ++i)
#pragma unroll
            for (int jj = 0; jj < 4; ++jj) {
                int m = mb + i * 16 + jj;
                out[(size_t)m * N + n] = acc[i][j][jj] + bb;
            }
    }
}

// ---------------------------------------------------------------------------
// MFMA flash attention v15: 16 barrier-phases of 2 key-tiles each
// (quad-buffered K/V pair ping-pong), P ENTIRELY IN REGISTERS:
// PV contracts keys in the lane-ownership order (valid: any key permutation
// works if P and V agree), so pf = lane-local cvt_pk packs (zero shuffles,
// zero P LDS) and V is read as two b64 chunks (keys 32ks+g*4 and +16.. +4)
// per (ks,nd) matching that order. 4 waves x 32 q, no-max softmax,
// pad bias as MFMA C-init (pbs LDS), XCD-aware grid. LDS 72KB, 2 blocks/CU.
// ---------------------------------------------------------------------------
__global__ __launch_bounds__(256, 2)
void attn_kernel(const unsigned short* __restrict__ Qh,
                 const unsigned short* __restrict__ Kh,
                 const unsigned short* __restrict__ Vt,
                 const float* __restrict__ padb,
                 unsigned short* __restrict__ ctx)
{
    __shared__ __align__(16) unsigned short Ks[4][64 * 64];   // 32KB
    __shared__ __align__(16) unsigned short Vs[4][64 * 64];   // 32KB
    __shared__ __align__(16) float pbs[T_];                   // 8KB

    const int tid  = threadIdx.x;
    const int w    = tid >> 6;        // 0..3
    const int l    = tid & 63;
    const int lo16 = l & 15;
    const int g    = l >> 4;
    const int lrow = l >> 3;          // 0..7
    const int lslot = (l & 7) ^ lrow; // pre-swizzled source slot

    // XCD-aware decode: blocks of one head cluster on one XCD's L2.
    const int f   = blockIdx.x;
    const int s   = f >> 3;
    const int bh  = (f & 7) * 4 + (s >> 4);
    const int q0  = (s & 15) * 128;
    const int bb  = bh >> 4;
    const int hh  = bh & 15;

    bf16x8 qf[2][2];
#pragma unroll
    for (int qt = 0; qt < 2; ++qt) {
        const unsigned short* Qp =
            Qh + ((size_t)bh * T_ + q0 + w * 32 + qt * 16 + lo16) * DM_ + g * 8;
        qf[qt][0] = *(const bf16x8*)(Qp);
        qf[qt][1] = *(const bf16x8*)(Qp + 32);
    }

    const unsigned short* kgp =
        Kh + (size_t)bh * T_ * DM_ + (size_t)(w * 16 + lrow) * DM_ + lslot * 8;
    const unsigned short* vgp =
        Vt + (size_t)bh * DM_ * T_ + (size_t)(w * 16 + lrow) * T_ + lslot * 8;

    // pad-bias table -> LDS once (2048 floats / 256 thr = 8 each)
    {
        const float* src = padb + bb * T_ + tid * 8;
        *(float4*)&pbs[tid * 8]     = *(const float4*)(src);
        *(float4*)&pbs[tid * 8 + 4] = *(const float4*)(src + 4);
    }

    // prologue: stage tiles 0,1 -> slots 0,1
    GLOAD16(kgp,                (char*)Ks[0] + (w * 16) * 128);
    GLOAD16(kgp + 8 * DM_,      (char*)Ks[0] + (w * 16 + 8) * 128);
    GLOAD16(kgp + 64 * DM_,     (char*)Ks[1] + (w * 16) * 128);
    GLOAD16(kgp + 72 * DM_,     (char*)Ks[1] + (w * 16 + 8) * 128);
    GLOAD16(vgp,                (char*)Vs[0] + (w * 16) * 128);
    GLOAD16(vgp + 8 * T_,       (char*)Vs[0] + (w * 16 + 8) * 128);
    GLOAD16(vgp + 64,           (char*)Vs[1] + (w * 16) * 128);
    GLOAD16(vgp + 8 * T_ + 64,  (char*)Vs[1] + (w * 16 + 8) * 128);
    kgp += 128 * DM_;
    vgp += 128;
    __syncthreads();

    f32x4 oa[2][4] = {};
    f32x4 ls4[2] = {};

    char* KrA = (char*)Ks[0]; char* KrB = (char*)Ks[1];
    char* KwA = (char*)Ks[2]; char* KwB = (char*)Ks[3];
    char* VrA = (char*)Vs[0]; char* VrB = (char*)Vs[1];
    char* VwA = (char*)Vs[2]; char* VwB = (char*)Vs[3];

    // one key-tile: QK (C-init=pad bias), exp2, lane-local pf packs, PV.
    auto process = [&](const char* Kt, const char* Vc, int pboff) {
        f32x4 sa[2][4];
#pragma unroll
        for (int nt = 0; nt < 4; ++nt) {
            f32x4 pb4 = *(const f32x4*)&pbs[pboff + nt * 16 + g * 4];
            sa[0][nt] = pb4;
            sa[1][nt] = pb4;
        }
        __builtin_amdgcn_s_setprio(1);
#pragma unroll
        for (int ks = 0; ks < 2; ++ks) {
#pragma unroll
            for (int nt = 0; nt < 4; ++nt) {
                int row = nt * 16 + lo16;
                int off = (row * 128 + ks * 64 + g * 16) ^ ((row & 7) << 4);
                bf16x8 kf = *(const bf16x8*)(Kt + off);
#pragma unroll
                for (int qt = 0; qt < 2; ++qt)
                    sa[qt][nt] = __builtin_amdgcn_mfma_f32_16x16x32_bf16(kf, qf[qt][ks], sa[qt][nt], 0, 0, 0);
            }
        }
        __builtin_amdgcn_s_setprio(0);

        // softmax: p = exp2(s); lsum += p; lane-local packs (key order = own)
        u32 pw[2][4][2];
#pragma unroll
        for (int qt = 0; qt < 2; ++qt)
#pragma unroll
            for (int nt = 0; nt < 4; ++nt) {
                float e0 = EXP2(sa[qt][nt][0]);
                float e1 = EXP2(sa[qt][nt][1]);
                float e2 = EXP2(sa[qt][nt][2]);
                float e3 = EXP2(sa[qt][nt][3]);
                ls4[qt] += (f32x4){e0, e1, e2, e3};
                pw[qt][nt][0] = pack2bf(e0, e1);
                pw[qt][nt][1] = pack2bf(e2, e3);
            }
        // pf[qt][ks] = keys {32ks+g*4..+3, 32ks+16+g*4..+3} (lane-local)
        bf16x8 pf[2][2];
#pragma unroll
        for (int qt = 0; qt < 2; ++qt)
#pragma unroll
            for (int ks = 0; ks < 2; ++ks) {
                uint4 uu;
                uu.x = pw[qt][2 * ks][0];
                uu.y = pw[qt][2 * ks][1];
                uu.z = pw[qt][2 * ks + 1][0];
                uu.w = pw[qt][2 * ks + 1][1];
                pf[qt][ks] = *(const bf16x8*)&uu;
            }

        // PV: V read in the SAME key order: two b64 chunks per (ks,nd)
        __builtin_amdgcn_s_setprio(1);
#pragma unroll
        for (int ks = 0; ks < 2; ++ks)
#pragma unroll
            for (int nd = 0; nd < 4; ++nd) {
                int row = nd * 16 + lo16;
                int sw = (row & 7) << 4;
                int o0 = (row * 128 + ks * 64 + g * 8) ^ sw;
                int o1 = (row * 128 + ks * 64 + 32 + g * 8) ^ sw;
                uint2 a = *(const uint2*)(Vc + o0);
                uint2 b = *(const uint2*)(Vc + o1);
                uint4 uu; uu.x = a.x; uu.y = a.y; uu.z = b.x; uu.w = b.y;
                bf16x8 vf = *(const bf16x8*)&uu;
#pragma unroll
                for (int qt = 0; qt < 2; ++qt)
                    oa[qt][nd] = __builtin_amdgcn_mfma_f32_16x16x32_bf16(vf, pf[qt][ks], oa[qt][nd], 0, 0, 0);
            }
        __builtin_amdgcn_s_setprio(0);
    };

    for (int p = 0; p < NP_; ++p) {
        if (p + 1 < NP_) {
            GLOAD16(kgp,               KwA + (w * 16) * 128);
            GLOAD16(kgp + 8 * DM_,     KwA + (w * 16 + 8) * 128);
            GLOAD16(kgp + 64 * DM_,    KwB + (w * 16) * 128);
            GLOAD16(kgp + 72 * DM_,    KwB + (w * 16 + 8) * 128);
            GLOAD16(vgp,               VwA + (w * 16) * 128);
            GLOAD16(vgp + 8 * T_,      VwA + (w * 16 + 8) * 128);
            GLOAD16(vgp + 64,          VwB + (w * 16) * 128);
            GLOAD16(vgp + 8 * T_ + 64, VwB + (w * 16 + 8) * 128);
            kgp += 128 * DM_;
            vgp += 128;
        }

        process(KrA, VrA, p * 128);        // tile 2p
        process(KrB, VrB, p * 128 + 64);   // tile 2p+1

        __syncthreads();
        { char* t0;
          t0 = KrA; KrA = KwA; KwA = t0;
          t0 = KrB; KrB = KwB; KwB = t0;
          t0 = VrA; VrA = VwA; VwA = t0;
          t0 = VrB; VrB = VwB; VwB = t0; }
    }

    // ---- epilogue: reduce l across g, write ctx
#pragma unroll
    for (int qt = 0; qt < 2; ++qt) {
        float lt = (ls4[qt][0] + ls4[qt][1]) + (ls4[qt][2] + ls4[qt][3]);
        lt += __shfl_xor(lt, 16);
        lt += __shfl_xor(lt, 32);
        float linv = 1.0f / lt;
        const size_t crow =
            ((size_t)(bb * T_ + q0 + w * 32 + qt * 16 + lo16)) * NQ_ + hh * DM_;
#pragma unroll
        for (int nd = 0; nd < 4; ++nd) {
            bf16x4 u = {bfc(oa[qt][nd][0] * linv), bfc(oa[qt][nd][1] * linv),
                        bfc(oa[qt][nd][2] * linv), bfc(oa[qt][nd][3] * linv)};
            *(bf16x4*)&ctx[crow + nd * 16 + g * 4] = u;
        }
    }
}

// ---------------------------------------------------------------------------
extern "C" void kernel_launch(void* const* d_in, const int* in_sizes, int n_in,
                              void* d_out, int out_size, void* d_ws, size_t ws_size,
                              hipStream_t stream) {
    const float* data = (const float*)d_in[0];
    const float* mask = (const float*)d_in[1];
    const float* wq   = (const float*)d_in[2];
    const float* bq   = (const float*)d_in[3];
    const float* wk   = (const float*)d_in[4];
    const float* bk   = (const float*)d_in[5];
    const float* wv   = (const float*)d_in[6];
    const float* bv   = (const float*)d_in[7];
    const float* wo   = (const float*)d_in[8];
    const float* bo   = (const float*)d_in[9];
    float* out = (float*)d_out;

    char* ws = (char*)d_ws;
    const size_t MB = 1024 * 1024;
    unsigned short* Qh    = (unsigned short*)(ws);             // 8MB
    unsigned short* Kh    = (unsigned short*)(ws +  8 * MB);   // 8MB
    unsigned short* Vt    = (unsigned short*)(ws + 16 * MB);   // 8MB
    unsigned short* CTX   = (unsigned short*)(ws + 24 * MB);   // 8MB (bf16)
    unsigned short* dataB = (unsigned short*)(ws + 32 * MB);   // 4MB
    unsigned short* BtAll = (unsigned short*)(ws + 36 * MB);   // 3MB
    unsigned short* wot   = (unsigned short*)(ws + 39 * MB);   // 1MB
    float*          padb  = (float*)         (ws + 40 * MB);   // 16KB

    const int M = B_ * T_;                 // 4096
    const float alpha_q = 0.125f * 1.44269504089f;

    prep_kernel<<<4096, 256, 0, stream>>>(mask, padb, data, dataB,
                                          wq, wk, wv, BtAll, wo, wot);

    mgemm_qkv_kernel<<<dim3(3 * NQ_ / 128, M / 128), 256, 0, stream>>>(
        dataB, BtAll, bq, bk, bv, Qh, Kh, Vt, alpha_q);

    attn_kernel<<<512, 256, 0, stream>>>(Qh, Kh, Vt, padb, CTX);

    mgemm_out_kernel<<<dim3(D_ / 128, M / 64), 256, 0, stream>>>(
        CTX, wot, bo, out, M, D_, NQ_);
}

// Round 16
// 98.817 us; speedup vs baseline: 1.1540x; 1.0653x over previous
//
#include <hip/hip_runtime.h>
#include <hip/hip_bf16.h>

#define B_  2
#define T_  2048
#define D_  512
#define DM_ 64
#define H_  16
#define NQ_ (DM_*H_)   // 1024
#define NP_ (T_/128)   // 16 phases (2 key-tiles each)

typedef __bf16 bf16x8 __attribute__((ext_vector_type(8)));
typedef __bf16 bf16x4 __attribute__((ext_vector_type(4)));
typedef float  f32x4  __attribute__((ext_vector_type(4)));
typedef unsigned int u32;

static __device__ __forceinline__ __bf16 bfc(float x) { return (__bf16)x; }
static __device__ __forceinline__ unsigned short f2bf(float x) {
    __bf16 b = (__bf16)x;
    unsigned short u;
    __builtin_memcpy(&u, &b, 2);
    return u;
}
static __device__ __forceinline__ u32 pack2bf(float a, float b) {
    return (u32)f2bf(a) | ((u32)f2bf(b) << 16);
}

#if __has_builtin(__builtin_amdgcn_exp2f)
static __device__ __forceinline__ float EXP2(float x) { return __builtin_amdgcn_exp2f(x); }
#else
static __device__ __forceinline__ float EXP2(float x) {
    float r; asm("v_exp_f32 %0, %1\ns_nop 0" : "=v"(r) : "v"(x)); return r;
}
#endif

// async global->LDS, 16B per lane; dest = wave-uniform base + lane*16
#define GLOAD16(gp, lp) \
    __builtin_amdgcn_global_load_lds((const __attribute__((address_space(1))) u32*)(gp), \
                                     (__attribute__((address_space(3))) u32*)(lp), 16, 0, 0)

// ---------------------------------------------------------------------------
// fused prep: [0,1024) pad | [1024,2048) data cvt | [2048,3584) qkv wtrans |
// [3584,4096) wo wtrans
// QKV wtrans writes PERMUTED rows: n' = h*64+dm  (head-major n-axis), i.e.
// btall row (c&15)*64 + (c>>4) for source column c.
// ---------------------------------------------------------------------------
__global__ __launch_bounds__(256)
void prep_kernel(const float* __restrict__ mask, float* __restrict__ padb,
                 const float* __restrict__ data, unsigned short* __restrict__ dataB,
                 const float* __restrict__ wq, const float* __restrict__ wk,
                 const float* __restrict__ wv, unsigned short* __restrict__ btall,
                 const float* __restrict__ wo, unsigned short* __restrict__ wot)
{
    __shared__ float t[32][33];
    const int bid = blockIdx.x;
    const int tid = threadIdx.x;
    if (bid < 1024) {
        const int row  = bid * 4 + (tid >> 6);
        const int lane = tid & 63;
        const float* p = mask + (size_t)row * D_;
        float4 a = *(const float4*)&p[lane * 8];
        float4 b = *(const float4*)&p[lane * 8 + 4];
        float s = a.x + a.y + a.z + a.w + b.x + b.y + b.z + b.w;
#pragma unroll
        for (int off = 32; off; off >>= 1) s += __shfl_down(s, off);
        if (lane == 0) padb[row] = (s == 0.0f) ? -1e9f : 0.0f;
    } else if (bid < 2048) {
        int i = ((bid - 1024) * 256 + tid) * 8;
        float4 a = *(const float4*)&data[i];
        float4 b = *(const float4*)&data[i + 4];
        bf16x8 u = {bfc(a.x), bfc(a.y), bfc(a.z), bfc(a.w),
                    bfc(b.x), bfc(b.y), bfc(b.z), bfc(b.w)};
        *(bf16x8*)&dataB[i] = u;
    } else if (bid < 3584) {
        const int idx = bid - 2048;
        const int z = idx >> 9, rem = idx & 511;
        const int c0 = (rem & 31) * 32, r0 = (rem >> 5) * 32;   // C=1024, R=512
        const float* in = (z == 0) ? wq : (z == 1) ? wk : wv;
        unsigned short* out = btall + (size_t)z * NQ_ * D_;
        const int tx = tid & 31, ty = tid >> 5;
#pragma unroll
        for (int i = 0; i < 4; ++i)
            t[ty * 4 + i][tx] = in[(size_t)(r0 + ty * 4 + i) * NQ_ + c0 + tx];
        __syncthreads();
#pragma unroll
        for (int i = 0; i < 4; ++i) {
            int c  = c0 + ty * 4 + i;
            int rp = (c & 15) * 64 + (c >> 4);   // n' = h*64 + dm
            out[(size_t)rp * D_ + r0 + tx] = f2bf(t[tx][ty * 4 + i]);
        }
    } else {
        const int idx = bid - 3584;
        const int c0 = (idx & 15) * 32, r0 = (idx >> 4) * 32;   // C=512, R=1024
        const int tx = tid & 31, ty = tid >> 5;
#pragma unroll
        for (int i = 0; i < 4; ++i)
            t[ty * 4 + i][tx] = wo[(size_t)(r0 + ty * 4 + i) * D_ + c0 + tx];
        __syncthreads();
#pragma unroll
        for (int i = 0; i < 4; ++i)
            wot[(size_t)(c0 + ty * 4 + i) * NQ_ + r0 + tx] = f2bf(t[tx][ty * 4 + i]);
    }
}

// ---------------------------------------------------------------------------
// fused QKV GEMM: A[4096,512] @ BtAll[3072,512]^T (n' = h*64+dm head-major).
// Each wave (wci) owns ONE head x 64 dm. Q/K epilogue: acc -> swizzled LDS
// scratch [128 m][64 dm] -> coalesced 16B/lane stores (8 lanes = 128B line).
// V epilogue: direct stores (t-contiguous 8B x 4-lane = 32B chunks).
// ---------------------------------------------------------------------------
__global__ __launch_bounds__(256)
void mgemm_qkv_kernel(const unsigned short* __restrict__ A,
                      const unsigned short* __restrict__ BtAll,
                      const float* __restrict__ bq, const float* __restrict__ bk,
                      const float* __restrict__ bv,
                      unsigned short* __restrict__ Qh, unsigned short* __restrict__ Kh,
                      unsigned short* __restrict__ Vt, float alpha_q)
{
    const int K = D_;
    __shared__ __align__(16) unsigned short Al[2][128 * 64];
    __shared__ __align__(16) unsigned short Bl[2][128 * 64];

    const int tid = threadIdx.x;
    const int w  = tid >> 6, l = tid & 63;
    const int lo = l & 15,  g = l >> 4;
    const int wri = w >> 1, wci = w & 1;
    const int m0 = blockIdx.y * 128, n0 = blockIdx.x * 128;
    const int lrow = l >> 3;
    const int lslot = (l & 7) ^ lrow;     // pre-swizzled source slot

    f32x4 acc[4][4] = {};
    const int nk = K >> 6;   // 8

    // prologue: stage k-step 0 into buf0
#pragma unroll
    for (int p = 0; p < 4; ++p) {
        int br = w * 32 + p * 8;
        GLOAD16(A     + (size_t)(m0 + br + lrow) * K + lslot * 8, (char*)Al[0] + br * 128);
        GLOAD16(BtAll + (size_t)(n0 + br + lrow) * K + lslot * 8, (char*)Bl[0] + br * 128);
    }
    __syncthreads();

    for (int t = 0; t < nk; ++t) {
        const int cur = t & 1;
        if (t + 1 < nk) {
            const int k0 = (t + 1) << 6;
#pragma unroll
            for (int p = 0; p < 4; ++p) {
                int br = w * 32 + p * 8;
                GLOAD16(A     + (size_t)(m0 + br + lrow) * K + k0 + lslot * 8,
                        (char*)Al[cur ^ 1] + br * 128);
                GLOAD16(BtAll + (size_t)(n0 + br + lrow) * K + k0 + lslot * 8,
                        (char*)Bl[cur ^ 1] + br * 128);
            }
        }
#pragma unroll
        for (int kk = 0; kk < 2; ++kk) {
            bf16x8 af[4], bfr[4];
#pragma unroll
            for (int i = 0; i < 4; ++i) {
                int row = wri * 64 + i * 16 + lo;
                af[i] = *(const bf16x8*)&Al[cur][row * 64 + ((((kk << 2) + g) ^ (row & 7)) << 3)];
                int col = wci * 64 + i * 16 + lo;
                bfr[i] = *(const bf16x8*)&Bl[cur][col * 64 + ((((kk << 2) + g) ^ (col & 7)) << 3)];
            }
#pragma unroll
            for (int i = 0; i < 4; ++i)
#pragma unroll
                for (int j = 0; j < 4; ++j)
                    acc[i][j] = __builtin_amdgcn_mfma_f32_16x16x32_bf16(af[i], bfr[j], acc[i][j], 0, 0, 0);
        }
        __syncthreads();
    }

    const int seg = n0 >> 10;                  // 0:Q 1:K 2:V
    const int n0l = n0 & 1023;
    const float* bias = (seg == 0) ? bq : (seg == 1) ? bk : bv;
    const float alpha = (seg == 0) ? alpha_q : 1.0f;
    const int h = (n0l >> 6) + wci;            // this wave's head

    // bias via inverse permutation: n' = h*64 + (j*16+lo)  ->  n = (j*16+lo)*16 + h
    float bb[4];
#pragma unroll
    for (int j = 0; j < 4; ++j) bb[j] = bias[(j * 16 + lo) * 16 + h];

    const int mb_l = wri * 64 + g * 4;         // local m base
    if (seg < 2) {
        unsigned short* o16 = (seg == 0) ? Qh : Kh;
        unsigned short* hb = (unsigned short*)Al + wci * (128 * 64);  // 16KB/head
        // scatter acc -> LDS [m][dm] (dm-chunk XOR swizzle)
#pragma unroll
        for (int i = 0; i < 4; ++i)
#pragma unroll
            for (int jj = 0; jj < 4; ++jj) {
                int ml = mb_l + i * 16 + jj;
#pragma unroll
                for (int j = 0; j < 4; ++j) {
                    int dm = j * 16 + lo;
                    int off = ml * 64 + (((dm >> 3) ^ (ml & 7)) << 3) + (dm & 7);
                    hb[off] = f2bf((acc[i][j][jj] + bb[j]) * alpha);
                }
            }
        __syncthreads();
        // coalesced: 8 passes x (b128 LDS read + 16B store; 8 lanes = 128B)
        const int rrow = l >> 3, rch = l & 7;
#pragma unroll
        for (int p = 0; p < 8; ++p) {
            int ml = wri * 64 + p * 8 + rrow;
            bf16x8 v = *(const bf16x8*)&hb[ml * 64 + (((rch ^ (ml & 7))) << 3)];
            int m = m0 + ml;
            int t = m & (T_ - 1), bidx = m >> 11;
            *(bf16x8*)&o16[(((size_t)(bidx * H_ + h)) * T_ + t) * DM_ + rch * 8] = v;
        }
    } else {
        // V^T [bh][dm][t]: per (i,j) 4 consecutive t at fixed dm (8B x 4-lane)
#pragma unroll
        for (int i = 0; i < 4; ++i)
#pragma unroll
            for (int j = 0; j < 4; ++j) {
                int m = m0 + mb_l + i * 16;
                int t = m & (T_ - 1), bidx = m >> 11;
                int dm = j * 16 + lo;
                bf16x4 u = {bfc(acc[i][j][0] + bb[j]), bfc(acc[i][j][1] + bb[j]),
                            bfc(acc[i][j][2] + bb[j]), bfc(acc[i][j][3] + bb[j])};
                *(bf16x4*)&Vt[((size_t)(bidx * H_ + h) * DM_ + dm) * T_ + t] = u;
            }
    }
}

// ---------------------------------------------------------------------------
// out-projection GEMM (fp32 out), 64x128 tile, gload_lds dbuf staging.
// ---------------------------------------------------------------------------
__global__ __launch_bounds__(256)
void mgemm_out_kernel(const unsigned short* __restrict__ A,
                      const unsigned short* __restrict__ Bt,
                      const float* __restrict__ bias, float* __restrict__ out,
                      int M, int N, int K)
{
    __shared__ __align__(16) unsigned short Al[2][64 * 64];
    __shared__ __align__(16) unsigned short Bl[2][128 * 64];

    const int tid = threadIdx.x;
    const int w  = tid >> 6, l = tid & 63;
    const int lo = l & 15,  g = l >> 4;
    const int wri = w >> 1, wci = w & 1;
    const int m0 = blockIdx.y * 64, n0 = blockIdx.x * 128;
    const int lrow = l >> 3;
    const int lslot = (l & 7) ^ lrow;

    f32x4 acc[2][4] = {};
    const int nk = K >> 6;

#pragma unroll
    for (int p = 0; p < 2; ++p) {
        int br = w * 16 + p * 8;
        GLOAD16(A + (size_t)(m0 + br + lrow) * K + lslot * 8, (char*)Al[0] + br * 128);
    }
#pragma unroll
    for (int p = 0; p < 4; ++p) {
        int br = w * 32 + p * 8;
        GLOAD16(Bt + (size_t)(n0 + br + lrow) * K + lslot * 8, (char*)Bl[0] + br * 128);
    }
    __syncthreads();

    for (int t = 0; t < nk; ++t) {
        const int cur = t & 1;
        if (t + 1 < nk) {
            const int k0 = (t + 1) << 6;
#pragma unroll
            for (int p = 0; p < 2; ++p) {
                int br = w * 16 + p * 8;
                GLOAD16(A + (size_t)(m0 + br + lrow) * K + k0 + lslot * 8,
                        (char*)Al[cur ^ 1] + br * 128);
            }
#pragma unroll
            for (int p = 0; p < 4; ++p) {
                int br = w * 32 + p * 8;
                GLOAD16(Bt + (size_t)(n0 + br + lrow) * K + k0 + lslot * 8,
                        (char*)Bl[cur ^ 1] + br * 128);
            }
        }
#pragma unroll
        for (int kk = 0; kk < 2; ++kk) {
            bf16x8 af[2], bfr[4];
#pragma unroll
            for (int i = 0; i < 2; ++i) {
                int row = wri * 32 + i * 16 + lo;
                af[i] = *(const bf16x8*)&Al[cur][row * 64 + ((((kk << 2) + g) ^ (row & 7)) << 3)];
            }
#pragma unroll
            for (int j = 0; j < 4; ++j) {
                int col = wci * 64 + j * 16 + lo;
                bfr[j] = *(const bf16x8*)&Bl[cur][col * 64 + ((((kk << 2) + g) ^ (col & 7)) << 3)];
            }
#pragma unroll
            for (int i = 0; i < 2; ++i)
#pragma unroll
                for (int j = 0; j < 4; ++j)
                    acc[i][j] = __builtin_amdgcn_mfma_f32_16x16x32_bf16(af[i], bfr[j], acc[i][j], 0, 0, 0);
        }
        __syncthreads();
    }

    const int mb = m0 + wri * 32 + g * 4;
#pragma unroll
    for (int j = 0; j < 4; ++j) {
        int n = n0 + wci * 64 + j * 16 + lo;
        float bb = bias[n];
#pragma unroll
        for (int i = 0; i < 2; ++i)
#pragma unroll
            for (int jj = 0; jj < 4; ++jj) {
                int m = mb + i * 16 + jj;
                out[(size_t)m * N + n] = acc[i][j][jj] + bb;
            }
    }
}

// ---------------------------------------------------------------------------
// MFMA flash attention v15 (unchanged from R15): 16 barrier-phases of 2
// key-tiles (quad-buffered pair ping-pong), P entirely in registers
// (lane-local key order, matching V b64-chunk reads), 4 waves x 32 q,
// no-max softmax, pad bias as MFMA C-init, XCD-aware grid.
// ---------------------------------------------------------------------------
__global__ __launch_bounds__(256, 2)
void attn_kernel(const unsigned short* __restrict__ Qh,
                 const unsigned short* __restrict__ Kh,
                 const unsigned short* __restrict__ Vt,
                 const float* __restrict__ padb,
                 unsigned short* __restrict__ ctx)
{
    __shared__ __align__(16) unsigned short Ks[4][64 * 64];   // 32KB
    __shared__ __align__(16) unsigned short Vs[4][64 * 64];   // 32KB
    __shared__ __align__(16) float pbs[T_];                   // 8KB

    const int tid  = threadIdx.x;
    const int w    = tid >> 6;        // 0..3
    const int l    = tid & 63;
    const int lo16 = l & 15;
    const int g    = l >> 4;
    const int lrow = l >> 3;          // 0..7
    const int lslot = (l & 7) ^ lrow; // pre-swizzled source slot

    const int f   = blockIdx.x;
    const int s   = f >> 3;
    const int bh  = (f & 7) * 4 + (s >> 4);
    const int q0  = (s & 15) * 128;
    const int bb  = bh >> 4;
    const int hh  = bh & 15;

    bf16x8 qf[2][2];
#pragma unroll
    for (int qt = 0; qt < 2; ++qt) {
        const unsigned short* Qp =
            Qh + ((size_t)bh * T_ + q0 + w * 32 + qt * 16 + lo16) * DM_ + g * 8;
        qf[qt][0] = *(const bf16x8*)(Qp);
        qf[qt][1] = *(const bf16x8*)(Qp + 32);
    }

    const unsigned short* kgp =
        Kh + (size_t)bh * T_ * DM_ + (size_t)(w * 16 + lrow) * DM_ + lslot * 8;
    const unsigned short* vgp =
        Vt + (size_t)bh * DM_ * T_ + (size_t)(w * 16 + lrow) * T_ + lslot * 8;

    {
        const float* src = padb + bb * T_ + tid * 8;
        *(float4*)&pbs[tid * 8]     = *(const float4*)(src);
        *(float4*)&pbs[tid * 8 + 4] = *(const float4*)(src + 4);
    }

    GLOAD16(kgp,                (char*)Ks[0] + (w * 16) * 128);
    GLOAD16(kgp + 8 * DM_,      (char*)Ks[0] + (w * 16 + 8) * 128);
    GLOAD16(kgp + 64 * DM_,     (char*)Ks[1] + (w * 16) * 128);
    GLOAD16(kgp + 72 * DM_,     (char*)Ks[1] + (w * 16 + 8) * 128);
    GLOAD16(vgp,                (char*)Vs[0] + (w * 16) * 128);
    GLOAD16(vgp + 8 * T_,       (char*)Vs[0] + (w * 16 + 8) * 128);
    GLOAD16(vgp + 64,           (char*)Vs[1] + (w * 16) * 128);
    GLOAD16(vgp + 8 * T_ + 64,  (char*)Vs[1] + (w * 16 + 8) * 128);
    kgp += 128 * DM_;
    vgp += 128;
    __syncthreads();

    f32x4 oa[2][4] = {};
    f32x4 ls4[2] = {};

    char* KrA = (char*)Ks[0]; char* KrB = (char*)Ks[1];
    char* KwA = (char*)Ks[2]; char* KwB = (char*)Ks[3];
    char* VrA = (char*)Vs[0]; char* VrB = (char*)Vs[1];
    char* VwA = (char*)Vs[2]; char* VwB = (char*)Vs[3];

    auto process = [&](const char* Kt, const char* Vc, int pboff) {
        f32x4 sa[2][4];
#pragma unroll
        for (int nt = 0; nt < 4; ++nt) {
            f32x4 pb4 = *(const f32x4*)&pbs[pboff + nt * 16 + g * 4];
            sa[0][nt] = pb4;
            sa[1][nt] = pb4;
        }
        __builtin_amdgcn_s_setprio(1);
#pragma unroll
        for (int ks = 0; ks < 2; ++ks) {
#pragma unroll
            for (int nt = 0; nt < 4; ++nt) {
                int row = nt * 16 + lo16;
                int off = (row * 128 + ks * 64 + g * 16) ^ ((row & 7) << 4);
                bf16x8 kf = *(const bf16x8*)(Kt + off);
#pragma unroll
                for (int qt = 0; qt < 2; ++qt)
                    sa[qt][nt] = __builtin_amdgcn_mfma_f32_16x16x32_bf16(kf, qf[qt][ks], sa[qt][nt], 0, 0, 0);
            }
        }
        __builtin_amdgcn_s_setprio(0);

        u32 pw[2][4][2];
#pragma unroll
        for (int qt = 0; qt < 2; ++qt)
#pragma unroll
            for (int nt = 0; nt < 4; ++nt) {
                float e0 = EXP2(sa[qt][nt][0]);
                float e1 = EXP2(sa[qt][nt][1]);
                float e2 = EXP2(sa[qt][nt][2]);
                float e3 = EXP2(sa[qt][nt][3]);
                ls4[qt] += (f32x4){e0, e1, e2, e3};
                pw[qt][nt][0] = pack2bf(e0, e1);
                pw[qt][nt][1] = pack2bf(e2, e3);
            }
        bf16x8 pf[2][2];
#pragma unroll
        for (int qt = 0; qt < 2; ++qt)
#pragma unroll
            for (int ks = 0; ks < 2; ++ks) {
                uint4 uu;
                uu.x = pw[qt][2 * ks][0];
                uu.y = pw[qt][2 * ks][1];
                uu.z = pw[qt][2 * ks + 1][0];
                uu.w = pw[qt][2 * ks + 1][1];
                pf[qt][ks] = *(const bf16x8*)&uu;
            }

        __builtin_amdgcn_s_setprio(1);
#pragma unroll
        for (int ks = 0; ks < 2; ++ks)
#pragma unroll
            for (int nd = 0; nd < 4; ++nd) {
                int row = nd * 16 + lo16;
                int sw = (row & 7) << 4;
                int o0 = (row * 128 + ks * 64 + g * 8) ^ sw;
                int o1 = (row * 128 + ks * 64 + 32 + g * 8) ^ sw;
                uint2 a = *(const uint2*)(Vc + o0);
                uint2 b = *(const uint2*)(Vc + o1);
                uint4 uu; uu.x = a.x; uu.y = a.y; uu.z = b.x; uu.w = b.y;
                bf16x8 vf = *(const bf16x8*)&uu;
#pragma unroll
                for (int qt = 0; qt < 2; ++qt)
                    oa[qt][nd] = __builtin_amdgcn_mfma_f32_16x16x32_bf16(vf, pf[qt][ks], oa[qt][nd], 0, 0, 0);
            }
        __builtin_amdgcn_s_setprio(0);
    };

    for (int p = 0; p < NP_; ++p) {
        if (p + 1 < NP_) {
            GLOAD16(kgp,               KwA + (w * 16) * 128);
            GLOAD16(kgp + 8 * DM_,     KwA + (w * 16 + 8) * 128);
            GLOAD16(kgp + 64 * DM_,    KwB + (w * 16) * 128);
            GLOAD16(kgp + 72 * DM_,    KwB + (w * 16 + 8) * 128);
            GLOAD16(vgp,               VwA + (w * 16) * 128);
            GLOAD16(vgp + 8 * T_,      VwA + (w * 16 + 8) * 128);
            GLOAD16(vgp + 64,          VwB + (w * 16) * 128);
            GLOAD16(vgp + 8 * T_ + 64, VwB + (w * 16 + 8) * 128);
            kgp += 128 * DM_;
            vgp += 128;
        }

        process(KrA, VrA, p * 128);
        process(KrB, VrB, p * 128 + 64);

        __syncthreads();
        { char* t0;
          t0 = KrA; KrA = KwA; KwA = t0;
          t0 = KrB; KrB = KwB; KwB = t0;
          t0 = VrA; VrA = VwA; VwA = t0;
          t0 = VrB; VrB = VwB; VwB = t0; }
    }

#pragma unroll
    for (int qt = 0; qt < 2; ++qt) {
        float lt = (ls4[qt][0] + ls4[qt][1]) + (ls4[qt][2] + ls4[qt][3]);
        lt += __shfl_xor(lt, 16);
        lt += __shfl_xor(lt, 32);
        float linv = 1.0f / lt;
        const size_t crow =
            ((size_t)(bb * T_ + q0 + w * 32 + qt * 16 + lo16)) * NQ_ + hh * DM_;
#pragma unroll
        for (int nd = 0; nd < 4; ++nd) {
            bf16x4 u = {bfc(oa[qt][nd][0] * linv), bfc(oa[qt][nd][1] * linv),
                        bfc(oa[qt][nd][2] * linv), bfc(oa[qt][nd][3] * linv)};
            *(bf16x4*)&ctx[crow + nd * 16 + g * 4] = u;
        }
    }
}

// ---------------------------------------------------------------------------
extern "C" void kernel_launch(void* const* d_in, const int* in_sizes, int n_in,
                              void* d_out, int out_size, void* d_ws, size_t ws_size,
                              hipStream_t stream) {
    const float* data = (const float*)d_in[0];
    const float* mask = (const float*)d_in[1];
    const float* wq   = (const float*)d_in[2];
    const float* bq   = (const float*)d_in[3];
    const float* wk   = (const float*)d_in[4];
    const float* bk   = (const float*)d_in[5];
    const float* wv   = (const float*)d_in[6];
    const float* bv   = (const float*)d_in[7];
    const float* wo   = (const float*)d_in[8];
    const float* bo   = (const float*)d_in[9];
    float* out = (float*)d_out;

    char* ws = (char*)d_ws;
    const size_t MB = 1024 * 1024;
    unsigned short* Qh    = (unsigned short*)(ws);             // 8MB
    unsigned short* Kh    = (unsigned short*)(ws +  8 * MB);   // 8MB
    unsigned short* Vt    = (unsigned short*)(ws + 16 * MB);   // 8MB
    unsigned short* CTX   = (unsigned short*)(ws + 24 * MB);   // 8MB (bf16)
    unsigned short* dataB = (unsigned short*)(ws + 32 * MB);   // 4MB
    unsigned short* BtAll = (unsigned short*)(ws + 36 * MB);   // 3MB
    unsigned short* wot   = (unsigned short*)(ws + 39 * MB);   // 1MB
    float*          padb  = (float*)         (ws + 40 * MB);   // 16KB

    const int M = B_ * T_;                 // 4096
    const float alpha_q = 0.125f * 1.44269504089f;

    prep_kernel<<<4096, 256, 0, stream>>>(mask, padb, data, dataB,
                                          wq, wk, wv, BtAll, wo, wot);

    mgemm_qkv_kernel<<<dim3(3 * NQ_ / 128, M / 128), 256, 0, stream>>>(
        dataB, BtAll, bq, bk, bv, Qh, Kh, Vt, alpha_q);

    attn_kernel<<<512, 256, 0, stream>>>(Qh, Kh, Vt, padb, CTX);

    mgemm_out_kernel<<<dim3(D_ / 128, M / 64), 256, 0, stream>>>(
        CTX, wot, bo, out, M, D_, NQ_);
}